// Round 12
// baseline (138.889 us; speedup 1.0000x reference)
//
#include <hip/hip_runtime.h>
#include <hip/hip_bf16.h>
#include <cstdint>
#include <cstddef>

// ---------------------------------------------------------------------------
// Fused MHA block: x@Wqkv^T -> RoPE -> causal flash attention -> @Wo^T
// B=2 S=2048 H=16 DK=64. fp32 in/out, bf16 MFMA compute (fp32 accum).
//
// R12: kernel-count reduction (verified loops untouched).
//  (a) prep_kernel = rope-table + 3x fp32->bf16 cvt in one launch.
//  (b) RoPE fused into QKV GEMM EPILOGUE (template EPI=2): block type
//      (Q/K/V) uniform via n0>>10; pairs via __shfl_xor(acc,1); rotate in
//      fp32; write q_r/k_r/vbuf directly. qkv intermediate (24MB) and rope
//      kernel's 24MB re-read eliminated. Small vtrans kernel (8MB) remains.
//  Launches 8 -> 5. GEMM K-loop = R9 (conflicts 0), attn = R11.
// ---------------------------------------------------------------------------

typedef unsigned short u16;
typedef unsigned int   u32;

typedef float f32x4 __attribute__((ext_vector_type(4)));
typedef short frag_t __attribute__((ext_vector_type(8)));

__device__ __forceinline__ f32x4 mfma16(frag_t a, frag_t b, f32x4 c) {
  return __builtin_amdgcn_mfma_f32_16x16x32_bf16(a, b, c, 0, 0, 0);
}

typedef __attribute__((address_space(1))) void as1_void;
typedef __attribute__((address_space(3))) void as3_void;
__device__ __forceinline__ void gload_lds16(const void* g, void* l) {
  __builtin_amdgcn_global_load_lds((as1_void*)g, (as3_void*)l, 16, 0, 0);
}

__device__ __forceinline__ u16 f2bf(float f) {  // RNE fp32 -> bf16
  u32 u = __builtin_bit_cast(u32, f);
  u += 0x7fffu + ((u >> 16) & 1u);
  return (u16)(u >> 16);
}
__device__ __forceinline__ float bf2f(u16 h) {
  u32 u = ((u32)h) << 16;
  return __builtin_bit_cast(float, u);
}
__device__ __forceinline__ u16 bf16u(float f) {  // via compiler cvt path
  __hip_bfloat16 h = __float2bfloat16(f);
  u16 u;
  __builtin_memcpy(&u, &h, 2);
  return u;
}
__device__ __forceinline__ float exp2_hw(float x) {  // raw v_exp_f32
  float r;
  asm("v_exp_f32 %0, %1" : "=v"(r) : "v"(x));
  return r;
}

static constexpr int Bb = 2, Ss = 2048, Hh = 16, Dd = 1024;
static constexpr int Mm = Bb * Ss;  // 4096
static constexpr int NT = Ss / 64;  // 32 k/q tiles

// ---------------------------------------------------------------------------
// 0) prep: rope cos/sin table + all three fp32->bf16 converts, one launch.
// ---------------------------------------------------------------------------
__global__ __launch_bounds__(256) void prep_kernel(const float* __restrict__ x,
                                                   const float* __restrict__ wqkv,
                                                   const float* __restrict__ wo,
                                                   u16* __restrict__ xb,
                                                   u16* __restrict__ wqkvb,
                                                   u16* __restrict__ wob,
                                                   float2* __restrict__ tab) {
  const int bid = blockIdx.x, tid = threadIdx.x;

  if (bid < 256) {  // rope table: 2048*32 entries, one per thread
    const int i = bid * 256 + tid;
    const int s = i >> 5, j = i & 31;
    const float log2_theta_over_32 = 0.41524101186091903f;  // log2(10000)/32
    float inv = exp2f(-(float)j * log2_theta_over_32);
    float fr = (float)s * inv;
    float sn, cs;
    sincosf(fr, &sn, &cs);
    tab[i] = make_float2(cs, sn);
  }

  // cvt: grid-stride over all three buffers (float4 granules)
  const int N1 = Mm * Dd / 4;            // 1048576  (x)
  const int N2 = N1 + 3 * Dd * Dd / 4;   // +786432  (Wqkv)
  const int N3 = N2 + Dd * Dd / 4;       // +262144  (Wo)
  for (int idx = bid * 256 + tid; idx < N3; idx += gridDim.x * 256) {
    const float4* src;
    u16* dst;
    int off;
    if (idx < N1)      { src = (const float4*)x;    dst = xb;    off = idx; }
    else if (idx < N2) { src = (const float4*)wqkv; dst = wqkvb; off = idx - N1; }
    else               { src = (const float4*)wo;   dst = wob;   off = idx - N2; }
    float4 v = src[off];
    ushort4 o;
    o.x = f2bf(v.x); o.y = f2bf(v.y); o.z = f2bf(v.z); o.w = f2bf(v.w);
    ((ushort4*)dst)[off] = o;
  }
}

// ---------------------------------------------------------------------------
// 1) GEMM C[m,n] = sum_k A[m,k] * B[n,k]
//    128x128 tile, dbuf LDS, T2 swizzle, T4 counted-vmcnt depth-2 pipeline
//    (R9 core, verified conflicts=0). EPI=0: fp32 C. EPI=2: fused RoPE
//    epilogue -> q_r (scaled), k_r, vbuf; no C matrix materialized.
// ---------------------------------------------------------------------------
template <int EPI>
__global__ __launch_bounds__(256) void gemm_bt_kernel(const u16* __restrict__ A,
                                                      const u16* __restrict__ Bm,
                                                      void* __restrict__ Cv,
                                                      int Mdim, int Ndim, int Kdim,
                                                      const float2* __restrict__ tab,
                                                      u16* __restrict__ q_r,
                                                      u16* __restrict__ k_r,
                                                      u16* __restrict__ vbuf) {
  __shared__ __align__(16) u16 As[2][128 * 64];
  __shared__ __align__(16) u16 Bs[2][128 * 64];
  const int tid = threadIdx.x;
  const int lane = tid & 63, wid = tid >> 6;
  const int wr = wid >> 1, wc = wid & 1;
  const int lr = lane & 15, lg = lane >> 4;

  // XCD-aware swizzle (T1): nwg % 8 == 0 for both launches (768, 256)
  const int nwg = gridDim.x * gridDim.y;
  const int orig = blockIdx.y * gridDim.x + blockIdx.x;
  const int cpx = nwg >> 3;
  const int swz = (orig & 7) * cpx + (orig >> 3);
  const int bx = swz % gridDim.x, by = swz / gridDim.x;
  const int m0 = by * 128, n0 = bx * 128;

  f32x4 acc[4][4] = {};

  // T2 (rule #21): LDS dest linear; global SOURCE granule pre-swizzled so
  // LDS(row, c) = Global(row, c ^ (row&7)).  row&7 == lane>>3 here.
  const int rowA = lane >> 3;
  const int colu = ((lane & 7) ^ rowA) * 8;  // u16 offset of 16B granule

  auto stage = [&](int buf, int kt) {
#pragma unroll
    for (int i = 0; i < 4; i++) {
      int chunk = wid * 4 + i;  // wave-uniform
      const u16* ga = A + (size_t)(m0 + chunk * 8 + rowA) * Kdim + kt + colu;
      gload_lds16(ga, &As[buf][chunk * 512]);
      const u16* gb = Bm + (size_t)(n0 + chunk * 8 + rowA) * Kdim + kt + colu;
      gload_lds16(gb, &Bs[buf][chunk * 512]);
    }
  };

  const int niter = Kdim >> 6;  // requires Kdim >= 128 (here: 1024)

  // prologue: fill both buffers, wait only for buf0's 8 loads
  stage(0, 0);
  stage(1, 64);
  asm volatile("s_waitcnt vmcnt(8)" ::: "memory");
  __builtin_amdgcn_sched_barrier(0);
  __builtin_amdgcn_s_barrier();
  __builtin_amdgcn_sched_barrier(0);

  const int rsw = (lr & 7) * 8;  // T2 read-side XOR (u16 units)
  int cur = 0;
  for (int it = 0; it < niter; ++it) {
#pragma unroll
    for (int ks = 0; ks < 2; ks++) {
      frag_t a[4], b[4];
#pragma unroll
      for (int mt = 0; mt < 4; mt++)
        a[mt] = *(const frag_t*)&As[cur][(wr * 64 + mt * 16 + lr) * 64 +
                                         ((ks * 32 + lg * 8) ^ rsw)];
#pragma unroll
      for (int nt = 0; nt < 4; nt++)
        b[nt] = *(const frag_t*)&Bs[cur][(wc * 64 + nt * 16 + lr) * 64 +
                                         ((ks * 32 + lg * 8) ^ rsw)];
#pragma unroll
      for (int mt = 0; mt < 4; mt++)
#pragma unroll
        for (int nt = 0; nt < 4; nt++)
          acc[mt][nt] = mfma16(a[mt], b[nt], acc[mt][nt]);
    }

    if (it + 1 < niter) {
      __builtin_amdgcn_s_barrier();      // all waves done reading buf cur
      __builtin_amdgcn_sched_barrier(0);
      if (it + 2 < niter) {
        stage(cur, (it + 2) << 6);       // refill just-read buf; 16 in flight
        asm volatile("s_waitcnt vmcnt(8)" ::: "memory");  // oldest 8 = next buf
      } else {
        asm volatile("s_waitcnt vmcnt(0)" ::: "memory");  // tail drain
      }
      __builtin_amdgcn_sched_barrier(0);
      __builtin_amdgcn_s_barrier();      // cross-wave: next buf visible
      __builtin_amdgcn_sched_barrier(0);
      cur ^= 1;
    }
  }

  if (EPI == 0) {
#pragma unroll
    for (int mt = 0; mt < 4; mt++)
#pragma unroll
      for (int nt = 0; nt < 4; nt++)
#pragma unroll
        for (int r = 0; r < 4; r++) {
          size_t row = (size_t)(m0 + wr * 64 + mt * 16 + lg * 4 + r);
          size_t col = (size_t)(n0 + wc * 64 + nt * 16 + lr);
          ((float*)Cv)[row * Ndim + col] = acc[mt][nt][r];
        }
  } else {  // EPI == 2: fused RoPE + QKV split epilogue
    const float qscale = 0.125f * 1.4426950408889634f;  // 1/sqrt(64)*log2(e)
    const int typ = n0 >> 10;  // 0=Q 1=K 2=V, uniform per block (128|1024)
#pragma unroll
    for (int mt = 0; mt < 4; mt++)
#pragma unroll
      for (int nt = 0; nt < 4; nt++)
#pragma unroll
        for (int r = 0; r < 4; r++) {
          const int row = m0 + wr * 64 + mt * 16 + lg * 4 + r;
          const int col = n0 + wc * 64 + nt * 16 + lr;
          const int s = row & (Ss - 1), bb = row >> 11;
          const int d = col & 63, hh = (col & 1023) >> 6;
          const size_t oaddr = (((size_t)bb * Hh + hh) * Ss + s) * 64 + d;
          const float a = acc[mt][nt][r];
          if (typ == 2) {
            vbuf[oaddr] = f2bf(a);
          } else {
            // pair partner: lane^1 holds col^1, same row, same (mt,nt,r)
            float part = __shfl_xor(a, 1);
            float2 cs = tab[s * 32 + (d >> 1)];
            // even d: a*cos - part*sin ; odd d: part*sin + a*cos
            float v = fmaf((d & 1) ? part : -part, cs.y, a * cs.x);
            if (typ == 0) v *= qscale;
            (typ == 0 ? q_r : k_r)[oaddr] = f2bf(v);
          }
        }
  }
}

// ---------------------------------------------------------------------------
// 2) V transpose: vbuf [bh][s][64] -> vt [bh][64][s]  (LDS tile, coalesced)
// ---------------------------------------------------------------------------
__global__ __launch_bounds__(256) void vtrans_kernel(const u16* __restrict__ vbuf,
                                                     u16* __restrict__ vt) {
  const int bh = blockIdx.y;
  const int s0 = blockIdx.x * 64;
  const int t = threadIdx.x;
  __shared__ __align__(16) u16 Vls[64 * 72];

  const int srow = t >> 2, c4 = t & 3;
  const size_t rb = ((size_t)bh * Ss + s0 + srow) * 64 + c4 * 16;
  *(uint4*)&Vls[srow * 72 + c4 * 16]     = *(const uint4*)(vbuf + rb);
  *(uint4*)&Vls[srow * 72 + c4 * 16 + 8] = *(const uint4*)(vbuf + rb + 8);
  __syncthreads();

  const int d = t >> 2, cq = t & 3;
  u16 ov[16] __attribute__((aligned(16)));
#pragma unroll
  for (int i = 0; i < 16; i++) ov[i] = Vls[(cq * 16 + i) * 72 + d];
  const size_t vb = ((size_t)bh * 64 + d) * Ss + s0 + cq * 16;
  *(uint4*)(vt + vb)     = *(uint4*)&ov[0];
  *(uint4*)(vt + vb + 8) = *(uint4*)&ov[8];
}

// ---------------------------------------------------------------------------
// 3) Flash attention (causal). R11: 8 waves/block (512 thr), paired q-tiles
//    (waves 0-3 = qtA, 4-7 = qtB), swapped QK^T, no max tracking, T2
//    XOR-swizzled stride-64 K/V/P LDS, double-buffered K/V, 1 barrier/iter.
// ---------------------------------------------------------------------------
__global__ __launch_bounds__(512, 4) void attn_kernel(const u16* __restrict__ q_r,
                                                      const u16* __restrict__ k_r,
                                                      const u16* __restrict__ vt,
                                                      u16* __restrict__ o) {
  const int pr = blockIdx.x;  // 0..15
  const int bh = blockIdx.y;
  const int b = bh >> 4, h = bh & 15;
  const int tid = threadIdx.x;
  const int lane = tid & 63, w = tid >> 6;
  const int ww = w & 3;
  const int lr = lane & 15, lg = lane >> 4;

  const int qt = (w < 4) ? pr : (NT - 1 - pr);  // this wave's q-tile
  const int qtB = NT - 1 - pr;                  // loop bound

  __shared__ __align__(16) u16 Ks[2][64 * 64];
  __shared__ __align__(16) u16 Vs[2][64 * 64];
  __shared__ __align__(16) u16 Ps[8][16 * 64];

  const size_t kvbase = (size_t)bh * Ss * 64;
  const size_t vtbase = (size_t)bh * 64 * Ss;
  u16* Pw = &Ps[w][0];
  const int qrow = ww * 16 + lr;
  const int sw = lr & 7;  // read-side row XOR key (frag rows = *+lr)

  // ---- Q fragments in registers (once) ----
  frag_t q0f, q1f;
  {
    const u16* qa = q_r + kvbase + (size_t)(qt * 64 + qrow) * 64 + lg * 8;
    q0f = *(const frag_t*)qa;
    q1f = *(const frag_t*)(qa + 32);
  }

  // staging: 512 threads, one 16B chunk per tensor; LDS granule swizzled
  const int srow = tid >> 3, sgr = tid & 7;
  const int scolg = sgr * 8;                     // global col (u16)
  const int scols = (sgr ^ (srow & 7)) * 8;      // swizzled LDS col (u16)
  uint4 kreg, vreg;
  const u16* kp = k_r + kvbase;
  const u16* vp = vt + vtbase;

  auto issue = [&](int kt) {
    kreg = *(const uint4*)(kp + (size_t)(kt * 64 + srow) * 64 + scolg);
    vreg = *(const uint4*)(vp + (size_t)srow * Ss + kt * 64 + scolg);
  };
  auto commit = [&](int buf) {
    *(uint4*)&Ks[buf][srow * 64 + scols] = kreg;
    *(uint4*)&Vs[buf][srow * 64 + scols] = vreg;
  };

  f32x4 oacc[4] = {};
  float l_run = 0.f;

  issue(0);
  commit(0);
  __syncthreads();

  for (int kt = 0; kt <= qtB; kt++) {
    const int cur = kt & 1;
    const bool last = (kt == qtB);
    if (!last) issue(kt + 1);  // next tile's loads in flight under compute

    if (kt <= qt) {  // wave-uniform
      // ---- S^T = K @ Q^T (swizzled K reads) ----
      f32x4 sa[4];
      __builtin_amdgcn_s_setprio(1);
#pragma unroll
      for (int kf = 0; kf < 4; kf++) {
        frag_t k0 = *(const frag_t*)&Ks[cur][(kf * 16 + lr) * 64 + ((lg ^ sw) * 8)];
        frag_t k1 = *(const frag_t*)&Ks[cur][(kf * 16 + lr) * 64 + (((4 + lg) ^ sw) * 8)];
        sa[kf] = mfma16(k0, q0f, f32x4{0.f, 0.f, 0.f, 0.f});
        sa[kf] = mfma16(k1, q1f, sa[kf]);
      }
      __builtin_amdgcn_s_setprio(0);

      if (kt == qt) {  // diagonal mask (uniform branch)
#pragma unroll
        for (int kf = 0; kf < 4; kf++)
#pragma unroll
          for (int r = 0; r < 4; r++)
            if (kf * 16 + lg * 4 + r > qrow) sa[kf][r] = -1e30f;
      }

      // ---- p = exp2(s), lane-local l, pack, write P (swizzled b64) ----
      float ls = 0.f;
#pragma unroll
      for (int kf = 0; kf < 4; kf++) {
        float p0 = exp2_hw(sa[kf][0]), p1 = exp2_hw(sa[kf][1]);
        float p2 = exp2_hw(sa[kf][2]), p3 = exp2_hw(sa[kf][3]);
        ls += (p0 + p1) + (p2 + p3);
        ushort4 w4;
        w4.x = bf16u(p0); w4.y = bf16u(p1); w4.z = bf16u(p2); w4.w = bf16u(p3);
        // k-range [kf*16+lg*4, +4) -> granule kf*2+(lg>>1), half lg&1
        const int pg = (kf * 2 + (lg >> 1)) ^ sw;
        *(ushort4*)&Pw[lr * 64 + pg * 8 + (lg & 1) * 4] = w4;
      }
      l_run += ls;

      // ---- PV from LDS P (swizzled reads) ----
      __builtin_amdgcn_s_setprio(1);
#pragma unroll
      for (int ks = 0; ks < 2; ks++) {
        frag_t pa = *(const frag_t*)&Pw[lr * 64 + (((ks * 4 + lg) ^ sw) * 8)];
#pragma unroll
        for (int df = 0; df < 4; df++) {
          frag_t bv = *(const frag_t*)&Vs[cur][(df * 16 + lr) * 64 +
                                               (((ks * 4 + lg) ^ sw) * 8)];
          oacc[df] = mfma16(pa, bv, oacc[df]);
        }
      }
      __builtin_amdgcn_s_setprio(0);
    }

    if (!last) commit(cur ^ 1);
    __syncthreads();
  }

  // ---- epilogue: reduce l across lg groups, O /= l, write bf16 ----
  l_run += __shfl_xor(l_run, 16);
  l_run += __shfl_xor(l_run, 32);
#pragma unroll
  for (int r = 0; r < 4; r++) {
    float il = 1.0f / __shfl(l_run, lg * 4 + r);
    size_t row = (size_t)b * Ss + qt * 64 + ww * 16 + lg * 4 + r;
#pragma unroll
    for (int df = 0; df < 4; df++)
      o[row * 1024 + h * 64 + df * 16 + lr] = f2bf(oacc[df][r] * il);
  }
}

// ---------------------------------------------------------------------------
// launch: prep -> gemm1(EPI=2, fused rope) -> vtrans -> attn -> gemm2(EPI=0)
// ---------------------------------------------------------------------------
extern "C" void kernel_launch(void* const* d_in, const int* in_sizes, int n_in,
                              void* d_out, int out_size, void* d_ws, size_t ws_size,
                              hipStream_t stream) {
  const float* x    = (const float*)d_in[0];
  const float* Wqkv = (const float*)d_in[1];
  const float* Wo   = (const float*)d_in[2];
  float* out = (float*)d_out;
  char* ws = (char*)d_ws;

  constexpr size_t TAB_OFF  = 0;                       // 512KB
  constexpr size_t XB_OFF   = TAB_OFF + 524288;        // 8MB
  constexpr size_t WQB_OFF  = XB_OFF + 8388608;        // 6MB
  constexpr size_t WOB_OFF  = WQB_OFF + 6291456;       // 2MB
  constexpr size_t VB_OFF   = WOB_OFF + 2097152;       // 8MB (vbuf)
  constexpr size_t QR_OFF   = VB_OFF + 8388608;        // 8MB
  constexpr size_t KR_OFF   = QR_OFF + 8388608;        // 8MB
  constexpr size_t VT_OFF   = KR_OFF + 8388608;        // 8MB
  constexpr size_t AO_OFF   = VT_OFF + 8388608;        // 8MB

  float2* tab = (float2*)(ws + TAB_OFF);
  u16* xb     = (u16*)(ws + XB_OFF);
  u16* wqkvb  = (u16*)(ws + WQB_OFF);
  u16* wob    = (u16*)(ws + WOB_OFF);
  u16* vbuf   = (u16*)(ws + VB_OFF);
  u16* q_r    = (u16*)(ws + QR_OFF);
  u16* k_r    = (u16*)(ws + KR_OFF);
  u16* vt     = (u16*)(ws + VT_OFF);
  u16* ao     = (u16*)(ws + AO_OFF);

  prep_kernel<<<2048, 256, 0, stream>>>(x, Wqkv, Wo, xb, wqkvb, wob, tab);

  // qkv = x @ Wqkv^T with fused RoPE epilogue -> q_r, k_r, vbuf
  gemm_bt_kernel<2><<<dim3(3 * Dd / 128, Mm / 128), 256, 0, stream>>>(
      xb, wqkvb, nullptr, Mm, 3 * Dd, Dd, tab, q_r, k_r, vbuf);

  vtrans_kernel<<<dim3(Ss / 64, Bb * Hh), 256, 0, stream>>>(vbuf, vt);

  attn_kernel<<<dim3(NT / 2, Bb * Hh), 512, 0, stream>>>(q_r, k_r, vt, ao);

  // out = attn @ Wo^T
  gemm_bt_kernel<0><<<dim3(Dd / 128, Mm / 128), 256, 0, stream>>>(
      ao, wob, out, Mm, Dd, Dd, nullptr, nullptr, nullptr, nullptr);
}

// Round 13
// 117.388 us; speedup vs baseline: 1.1832x; 1.1832x over previous
//
#include <hip/hip_runtime.h>
#include <hip/hip_bf16.h>
#include <cstdint>
#include <cstddef>

// ---------------------------------------------------------------------------
// Fused MHA block: x@Wqkv^T -> RoPE -> causal flash attention -> @Wo^T
// B=2 S=2048 H=16 DK=64. fp32 in/out, bf16 MFMA compute (fp32 accum).
//
// R13: revert R12's rope-fusion (cost +22us on QKV); keep prep fusion.
// NEW: QKV GEMM ported to the 8-phase 256^2 schedule (T2+T3+T4+T5, m201):
//   - BM=BN=256 BK=64, 8 waves (2x4), acc[8][4], 128KB dynamic LDS dbuf.
//   - per K-tile 4 phases: {ds_read A-quad(+B at ph0); barrier; setprio+
//     16 MFMA; barrier}. Stage into liveness windows: B(kt+2) at ph1/ph2
//     (B region dead after ph0), A(kt+2) at K-tile boundary (dead after
//     ph3), then counted vmcnt(8) == "kt+1 fully resident" (in-order
//     retire; ledger: B(kt+1),A(kt+1),B(kt+2),A(kt+2)=16 outstanding).
//   - R9-verified XOR swizzle (zero-conflict) on both write and read.
// rope/attn/Wo-GEMM = R11 verbatim (verified). Launches: 5.
// ---------------------------------------------------------------------------

typedef unsigned short u16;
typedef unsigned int   u32;

typedef float f32x4 __attribute__((ext_vector_type(4)));
typedef short frag_t __attribute__((ext_vector_type(8)));

__device__ __forceinline__ f32x4 mfma16(frag_t a, frag_t b, f32x4 c) {
  return __builtin_amdgcn_mfma_f32_16x16x32_bf16(a, b, c, 0, 0, 0);
}

typedef __attribute__((address_space(1))) void as1_void;
typedef __attribute__((address_space(3))) void as3_void;
__device__ __forceinline__ void gload_lds16(const void* g, void* l) {
  __builtin_amdgcn_global_load_lds((as1_void*)g, (as3_void*)l, 16, 0, 0);
}

__device__ __forceinline__ u16 f2bf(float f) {  // RNE fp32 -> bf16
  u32 u = __builtin_bit_cast(u32, f);
  u += 0x7fffu + ((u >> 16) & 1u);
  return (u16)(u >> 16);
}
__device__ __forceinline__ float bf2f(u16 h) {
  u32 u = ((u32)h) << 16;
  return __builtin_bit_cast(float, u);
}
__device__ __forceinline__ u16 bf16u(float f) {  // via compiler cvt path
  __hip_bfloat16 h = __float2bfloat16(f);
  u16 u;
  __builtin_memcpy(&u, &h, 2);
  return u;
}
__device__ __forceinline__ float exp2_hw(float x) {  // raw v_exp_f32
  float r;
  asm("v_exp_f32 %0, %1" : "=v"(r) : "v"(x));
  return r;
}
__device__ __forceinline__ void schedb() { __builtin_amdgcn_sched_barrier(0); }

static constexpr int Bb = 2, Ss = 2048, Hh = 16, Dd = 1024;
static constexpr int Mm = Bb * Ss;  // 4096
static constexpr int NT = Ss / 64;  // 32 k/q tiles

// ---------------------------------------------------------------------------
// 0) prep: rope cos/sin table + all three fp32->bf16 converts, one launch.
// ---------------------------------------------------------------------------
__global__ __launch_bounds__(256) void prep_kernel(const float* __restrict__ x,
                                                   const float* __restrict__ wqkv,
                                                   const float* __restrict__ wo,
                                                   u16* __restrict__ xb,
                                                   u16* __restrict__ wqkvb,
                                                   u16* __restrict__ wob,
                                                   float2* __restrict__ tab) {
  const int bid = blockIdx.x, tid = threadIdx.x;

  if (bid < 256) {  // rope table: 2048*32 entries, one per thread
    const int i = bid * 256 + tid;
    const int s = i >> 5, j = i & 31;
    const float log2_theta_over_32 = 0.41524101186091903f;  // log2(10000)/32
    float inv = exp2f(-(float)j * log2_theta_over_32);
    float fr = (float)s * inv;
    float sn, cs;
    sincosf(fr, &sn, &cs);
    tab[i] = make_float2(cs, sn);
  }

  const int N1 = Mm * Dd / 4;
  const int N2 = N1 + 3 * Dd * Dd / 4;
  const int N3 = N2 + Dd * Dd / 4;
  for (int idx = bid * 256 + tid; idx < N3; idx += gridDim.x * 256) {
    const float4* src;
    u16* dst;
    int off;
    if (idx < N1)      { src = (const float4*)x;    dst = xb;    off = idx; }
    else if (idx < N2) { src = (const float4*)wqkv; dst = wqkvb; off = idx - N1; }
    else               { src = (const float4*)wo;   dst = wob;   off = idx - N2; }
    float4 v = src[off];
    ushort4 o;
    o.x = f2bf(v.x); o.y = f2bf(v.y); o.z = f2bf(v.z); o.w = f2bf(v.w);
    ((ushort4*)dst)[off] = o;
  }
}

// ---------------------------------------------------------------------------
// 1a) QKV GEMM: 8-phase 256x256 schedule. C[m,n]=sum_k A[m,k]B[n,k], bf16 out.
// ---------------------------------------------------------------------------
__global__ __launch_bounds__(512, 2) void gemm8_kernel(const u16* __restrict__ A,
                                                       const u16* __restrict__ Bm,
                                                       u16* __restrict__ C,
                                                       int Mdim, int Ndim, int Kdim) {
  extern __shared__ __align__(16) u16 smem[];
  u16* As0 = smem;              // [256][64]
  u16* As1 = smem + 16384;
  u16* Bs0 = smem + 32768;
  u16* Bs1 = smem + 49152;

  const int tid = threadIdx.x;
  const int lane = tid & 63, wid = tid >> 6;  // 8 waves
  const int wr = wid >> 2, wc = wid & 3;      // 2 x 4
  const int lr = lane & 15, lg = lane >> 4;
  const int swk = lr & 7;                     // read-side XOR key

  // T1 XCD swizzle (nwg = 192, %8 == 0)
  const int nwg = gridDim.x * gridDim.y;
  const int orig = blockIdx.y * gridDim.x + blockIdx.x;
  const int cpx = nwg >> 3;
  const int swz = (orig & 7) * cpx + (orig >> 3);
  const int bx = swz % gridDim.x, by = swz / gridDim.x;
  const int m0 = by * 256, n0 = bx * 256;

  f32x4 acc[8][4] = {};

  const int strow = tid >> 3;  // 0..63
  const int sgr = tid & 7;

  // half-tile stage: 128 rows x 64 cols, 2 gload_lds rounds; linear LDS dest,
  // pre-swizzled global source granule (rule 21; R9-verified zero-conflict)
  auto stage_half = [&](u16* region, const u16* src, int grow0, int kt) {
#pragma unroll
    for (int rnd = 0; rnd < 2; rnd++) {
      const int lrow = rnd * 64 + strow;
      const u16* g = src + (size_t)(grow0 + lrow) * Kdim + kt * 64 +
                     ((sgr ^ (lrow & 7)) * 8);
      gload_lds16(g, region + (rnd * 64 + wid * 8) * 64);
    }
  };

  const int NK = Kdim >> 6;  // 16

  // prologue: kt0 (A0,A1,B0,B1) then kt1 (B0,B1,A0,A1) = 16 loads/thread
  stage_half(As0, A, m0, 0);         stage_half(As0 + 8192, A, m0 + 128, 0);
  stage_half(Bs0, Bm, n0, 0);        stage_half(Bs0 + 8192, Bm, n0 + 128, 0);
  stage_half(Bs1, Bm, n0, 1);        stage_half(Bs1 + 8192, Bm, n0 + 128, 1);
  stage_half(As1, A, m0, 1);         stage_half(As1 + 8192, A, m0 + 128, 1);
  asm volatile("s_waitcnt vmcnt(8)" ::: "memory");  // kt0 resident
  schedb();
  __builtin_amdgcn_s_barrier();
  schedb();

  for (int kt = 0; kt < NK; kt++) {
    u16* Acur = (kt & 1) ? As1 : As0;
    u16* Bcur = (kt & 1) ? Bs1 : Bs0;
    const bool more = (kt + 2 < NK);
    frag_t bfr[4][2];

#pragma unroll
    for (int q = 0; q < 4; q++) {
      // ds_read: A quadrant q (2 m-rows x 2 ks); B all frags at phase 0
      frag_t a[2][2];
#pragma unroll
      for (int mm = 0; mm < 2; mm++)
#pragma unroll
        for (int ks = 0; ks < 2; ks++)
          a[mm][ks] = *(const frag_t*)&Acur[(wr * 128 + (q * 2 + mm) * 16 + lr) * 64 +
                                            (((ks * 4 + lg) ^ swk) * 8)];
      if (q == 0) {
#pragma unroll
        for (int nt = 0; nt < 4; nt++)
#pragma unroll
          for (int ks = 0; ks < 2; ks++)
            bfr[nt][ks] = *(const frag_t*)&Bcur[(wc * 64 + nt * 16 + lr) * 64 +
                                                (((ks * 4 + lg) ^ swk) * 8)];
      }
      // stage B(kt+2) into the B region (dead after phase 0's barrier pair)
      if (q == 1 && more) stage_half(Bcur, Bm, n0, kt + 2);
      if (q == 2 && more) stage_half(Bcur + 8192, Bm, n0 + 128, kt + 2);

      schedb();
      __builtin_amdgcn_s_barrier();
      schedb();
      __builtin_amdgcn_s_setprio(1);
#pragma unroll
      for (int ks = 0; ks < 2; ks++)
#pragma unroll
        for (int mm = 0; mm < 2; mm++)
#pragma unroll
          for (int nt = 0; nt < 4; nt++)
            acc[q * 2 + mm][nt] = mfma16(a[mm][ks], bfr[nt][ks], acc[q * 2 + mm][nt]);
      __builtin_amdgcn_s_setprio(0);
      __builtin_amdgcn_s_barrier();
      schedb();
    }

    // K-tile boundary: A region of buf[cur] now dead -> stage A(kt+2);
    // counted vmcnt(8) == kt+1 fully resident (in-order retirement).
    if (kt + 1 < NK) {
      if (more) {
        stage_half(Acur, A, m0, kt + 2);
        stage_half(Acur + 8192, A, m0 + 128, kt + 2);
        asm volatile("s_waitcnt vmcnt(8)" ::: "memory");
      } else {
        asm volatile("s_waitcnt vmcnt(0)" ::: "memory");  // tail drain
      }
      schedb();
      __builtin_amdgcn_s_barrier();
      schedb();
    }
  }

  // epilogue: bf16 C write
#pragma unroll
  for (int m = 0; m < 8; m++)
#pragma unroll
    for (int n = 0; n < 4; n++)
#pragma unroll
      for (int r = 0; r < 4; r++) {
        size_t row = (size_t)(m0 + wr * 128 + m * 16 + lg * 4 + r);
        size_t col = (size_t)(n0 + wc * 64 + n * 16 + lr);
        C[row * Ndim + col] = f2bf(acc[m][n][r]);
      }
}

// ---------------------------------------------------------------------------
// 1b) Wo GEMM: R9/R11 128x128 2-phase kernel (verified conflicts=0), fp32 out.
// ---------------------------------------------------------------------------
__global__ __launch_bounds__(256) void gemm_bt_kernel(const u16* __restrict__ A,
                                                      const u16* __restrict__ Bm,
                                                      float* __restrict__ Cv,
                                                      int Mdim, int Ndim, int Kdim) {
  __shared__ __align__(16) u16 As[2][128 * 64];
  __shared__ __align__(16) u16 Bs[2][128 * 64];
  const int tid = threadIdx.x;
  const int lane = tid & 63, wid = tid >> 6;
  const int wr = wid >> 1, wc = wid & 1;
  const int lr = lane & 15, lg = lane >> 4;

  const int nwg = gridDim.x * gridDim.y;
  const int orig = blockIdx.y * gridDim.x + blockIdx.x;
  const int cpx = nwg >> 3;
  const int swz = (orig & 7) * cpx + (orig >> 3);
  const int bx = swz % gridDim.x, by = swz / gridDim.x;
  const int m0 = by * 128, n0 = bx * 128;

  f32x4 acc[4][4] = {};

  const int rowA = lane >> 3;
  const int colu = ((lane & 7) ^ rowA) * 8;

  auto stage = [&](int buf, int kt) {
#pragma unroll
    for (int i = 0; i < 4; i++) {
      int chunk = wid * 4 + i;
      const u16* ga = A + (size_t)(m0 + chunk * 8 + rowA) * Kdim + kt + colu;
      gload_lds16(ga, &As[buf][chunk * 512]);
      const u16* gb = Bm + (size_t)(n0 + chunk * 8 + rowA) * Kdim + kt + colu;
      gload_lds16(gb, &Bs[buf][chunk * 512]);
    }
  };

  const int niter = Kdim >> 6;

  stage(0, 0);
  stage(1, 64);
  asm volatile("s_waitcnt vmcnt(8)" ::: "memory");
  schedb();
  __builtin_amdgcn_s_barrier();
  schedb();

  const int rsw = (lr & 7) * 8;
  int cur = 0;
  for (int it = 0; it < niter; ++it) {
#pragma unroll
    for (int ks = 0; ks < 2; ks++) {
      frag_t a[4], b[4];
#pragma unroll
      for (int mt = 0; mt < 4; mt++)
        a[mt] = *(const frag_t*)&As[cur][(wr * 64 + mt * 16 + lr) * 64 +
                                         ((ks * 32 + lg * 8) ^ rsw)];
#pragma unroll
      for (int nt = 0; nt < 4; nt++)
        b[nt] = *(const frag_t*)&Bs[cur][(wc * 64 + nt * 16 + lr) * 64 +
                                         ((ks * 32 + lg * 8) ^ rsw)];
#pragma unroll
      for (int mt = 0; mt < 4; mt++)
#pragma unroll
        for (int nt = 0; nt < 4; nt++)
          acc[mt][nt] = mfma16(a[mt], b[nt], acc[mt][nt]);
    }

    if (it + 1 < niter) {
      __builtin_amdgcn_s_barrier();
      schedb();
      if (it + 2 < niter) {
        stage(cur, (it + 2) << 6);
        asm volatile("s_waitcnt vmcnt(8)" ::: "memory");
      } else {
        asm volatile("s_waitcnt vmcnt(0)" ::: "memory");
      }
      schedb();
      __builtin_amdgcn_s_barrier();
      schedb();
      cur ^= 1;
    }
  }

#pragma unroll
  for (int mt = 0; mt < 4; mt++)
#pragma unroll
    for (int nt = 0; nt < 4; nt++)
#pragma unroll
      for (int r = 0; r < 4; r++) {
        size_t row = (size_t)(m0 + wr * 64 + mt * 16 + lg * 4 + r);
        size_t col = (size_t)(n0 + wc * 64 + nt * 16 + lr);
        Cv[row * Ndim + col] = acc[mt][nt][r];
      }
}

// ---------------------------------------------------------------------------
// 2) RoPE + reshape (R11 verbatim). Q pre-scaled by 0.125*log2(e).
// ---------------------------------------------------------------------------
__global__ __launch_bounds__(256) void rope_kernel(const u16* __restrict__ qkv,
                                                   const float2* __restrict__ tab,
                                                   u16* __restrict__ q_r,
                                                   u16* __restrict__ k_r,
                                                   u16* __restrict__ vt) {
  const int bh = blockIdx.y, b = bh >> 4, h = bh & 15;
  const int s0 = blockIdx.x * 64;
  const int t = threadIdx.x;
  __shared__ __align__(16) u16 Vls[64 * 72];

  const int srow = t >> 2, c4 = t & 3;
  const int s = s0 + srow;
  const size_t rowbase = (size_t)(b * Ss + s) * 3072 + h * 64 + c4 * 16;

  u16 xq[16] __attribute__((aligned(16)));
  u16 xk[16] __attribute__((aligned(16)));
  u16 xv[16] __attribute__((aligned(16)));
  *(uint4*)&xq[0] = *(const uint4*)(qkv + rowbase);
  *(uint4*)&xq[8] = *(const uint4*)(qkv + rowbase + 8);
  *(uint4*)&xk[0] = *(const uint4*)(qkv + rowbase + 1024);
  *(uint4*)&xk[8] = *(const uint4*)(qkv + rowbase + 1024 + 8);
  *(uint4*)&xv[0] = *(const uint4*)(qkv + rowbase + 2048);
  *(uint4*)&xv[8] = *(const uint4*)(qkv + rowbase + 2048 + 8);

  u16 oq[16] __attribute__((aligned(16)));
  u16 ok[16] __attribute__((aligned(16)));
  const int j0 = c4 * 8;
  const float qscale = 0.125f * 1.4426950408889634f;  // 1/sqrt(64) * log2(e)
#pragma unroll
  for (int p = 0; p < 8; p++) {
    float2 cs = tab[s * 32 + j0 + p];
    float q1 = bf2f(xq[2 * p]), q2 = bf2f(xq[2 * p + 1]);
    float k1 = bf2f(xk[2 * p]), k2 = bf2f(xk[2 * p + 1]);
    oq[2 * p]     = f2bf((q1 * cs.x - q2 * cs.y) * qscale);
    oq[2 * p + 1] = f2bf((q1 * cs.y + q2 * cs.x) * qscale);
    ok[2 * p]     = f2bf(k1 * cs.x - k2 * cs.y);
    ok[2 * p + 1] = f2bf(k1 * cs.y + k2 * cs.x);
  }
  const size_t obase = ((size_t)bh * Ss + s) * 64 + c4 * 16;
  *(uint4*)(q_r + obase)     = *(uint4*)&oq[0];
  *(uint4*)(q_r + obase + 8) = *(uint4*)&oq[8];
  *(uint4*)(k_r + obase)     = *(uint4*)&ok[0];
  *(uint4*)(k_r + obase + 8) = *(uint4*)&ok[8];

  *(uint4*)&Vls[srow * 72 + c4 * 16]     = *(uint4*)&xv[0];
  *(uint4*)&Vls[srow * 72 + c4 * 16 + 8] = *(uint4*)&xv[8];
  __syncthreads();
  const int d = t >> 2, cq = t & 3;
  u16 ov[16] __attribute__((aligned(16)));
#pragma unroll
  for (int i = 0; i < 16; i++) ov[i] = Vls[(cq * 16 + i) * 72 + d];
  const size_t vbase = ((size_t)bh * 64 + d) * Ss + s0 + cq * 16;
  *(uint4*)(vt + vbase)     = *(uint4*)&ov[0];
  *(uint4*)(vt + vbase + 8) = *(uint4*)&ov[8];
}

// ---------------------------------------------------------------------------
// 3) Flash attention (R11 verbatim): 8 waves/block, paired q-tiles, swapped
//    QK^T, no max tracking, T2 XOR-swizzled stride-64 K/V/P LDS, dbuf K/V.
// ---------------------------------------------------------------------------
__global__ __launch_bounds__(512, 4) void attn_kernel(const u16* __restrict__ q_r,
                                                      const u16* __restrict__ k_r,
                                                      const u16* __restrict__ vt,
                                                      u16* __restrict__ o) {
  const int pr = blockIdx.x;  // 0..15
  const int bh = blockIdx.y;
  const int b = bh >> 4, h = bh & 15;
  const int tid = threadIdx.x;
  const int lane = tid & 63, w = tid >> 6;
  const int ww = w & 3;
  const int lr = lane & 15, lg = lane >> 4;

  const int qt = (w < 4) ? pr : (NT - 1 - pr);
  const int qtB = NT - 1 - pr;

  __shared__ __align__(16) u16 Ks[2][64 * 64];
  __shared__ __align__(16) u16 Vs[2][64 * 64];
  __shared__ __align__(16) u16 Ps[8][16 * 64];

  const size_t kvbase = (size_t)bh * Ss * 64;
  const size_t vtbase = (size_t)bh * 64 * Ss;
  u16* Pw = &Ps[w][0];
  const int qrow = ww * 16 + lr;
  const int sw = lr & 7;

  frag_t q0f, q1f;
  {
    const u16* qa = q_r + kvbase + (size_t)(qt * 64 + qrow) * 64 + lg * 8;
    q0f = *(const frag_t*)qa;
    q1f = *(const frag_t*)(qa + 32);
  }

  const int srow = tid >> 3, sgr = tid & 7;
  const int scolg = sgr * 8;
  const int scols = (sgr ^ (srow & 7)) * 8;
  uint4 kreg, vreg;
  const u16* kp = k_r + kvbase;
  const u16* vp = vt + vtbase;

  auto issue = [&](int kt) {
    kreg = *(const uint4*)(kp + (size_t)(kt * 64 + srow) * 64 + scolg);
    vreg = *(const uint4*)(vp + (size_t)srow * Ss + kt * 64 + scolg);
  };
  auto commit = [&](int buf) {
    *(uint4*)&Ks[buf][srow * 64 + scols] = kreg;
    *(uint4*)&Vs[buf][srow * 64 + scols] = vreg;
  };

  f32x4 oacc[4] = {};
  float l_run = 0.f;

  issue(0);
  commit(0);
  __syncthreads();

  for (int kt = 0; kt <= qtB; kt++) {
    const int cur = kt & 1;
    const bool last = (kt == qtB);
    if (!last) issue(kt + 1);

    if (kt <= qt) {
      f32x4 sa[4];
      __builtin_amdgcn_s_setprio(1);
#pragma unroll
      for (int kf = 0; kf < 4; kf++) {
        frag_t k0 = *(const frag_t*)&Ks[cur][(kf * 16 + lr) * 64 + ((lg ^ sw) * 8)];
        frag_t k1 = *(const frag_t*)&Ks[cur][(kf * 16 + lr) * 64 + (((4 + lg) ^ sw) * 8)];
        sa[kf] = mfma16(k0, q0f, f32x4{0.f, 0.f, 0.f, 0.f});
        sa[kf] = mfma16(k1, q1f, sa[kf]);
      }
      __builtin_amdgcn_s_setprio(0);

      if (kt == qt) {
#pragma unroll
        for (int kf = 0; kf < 4; kf++)
#pragma unroll
          for (int r = 0; r < 4; r++)
            if (kf * 16 + lg * 4 + r > qrow) sa[kf][r] = -1e30f;
      }

      float ls = 0.f;
#pragma unroll
      for (int kf = 0; kf < 4; kf++) {
        float p0 = exp2_hw(sa[kf][0]), p1 = exp2_hw(sa[kf][1]);
        float p2 = exp2_hw(sa[kf][2]), p3 = exp2_hw(sa[kf][3]);
        ls += (p0 + p1) + (p2 + p3);
        ushort4 w4;
        w4.x = bf16u(p0); w4.y = bf16u(p1); w4.z = bf16u(p2); w4.w = bf16u(p3);
        const int pg = (kf * 2 + (lg >> 1)) ^ sw;
        *(ushort4*)&Pw[lr * 64 + pg * 8 + (lg & 1) * 4] = w4;
      }
      l_run += ls;

      __builtin_amdgcn_s_setprio(1);
#pragma unroll
      for (int ks = 0; ks < 2; ks++) {
        frag_t pa = *(const frag_t*)&Pw[lr * 64 + (((ks * 4 + lg) ^ sw) * 8)];
#pragma unroll
        for (int df = 0; df < 4; df++) {
          frag_t bv = *(const frag_t*)&Vs[cur][(df * 16 + lr) * 64 +
                                               (((ks * 4 + lg) ^ sw) * 8)];
          oacc[df] = mfma16(pa, bv, oacc[df]);
        }
      }
      __builtin_amdgcn_s_setprio(0);
    }

    if (!last) commit(cur ^ 1);
    __syncthreads();
  }

  l_run += __shfl_xor(l_run, 16);
  l_run += __shfl_xor(l_run, 32);
#pragma unroll
  for (int r = 0; r < 4; r++) {
    float il = 1.0f / __shfl(l_run, lg * 4 + r);
    size_t row = (size_t)b * Ss + qt * 64 + ww * 16 + lg * 4 + r;
#pragma unroll
    for (int df = 0; df < 4; df++)
      o[row * 1024 + h * 64 + df * 16 + lr] = f2bf(oacc[df][r] * il);
  }
}

// ---------------------------------------------------------------------------
// launch: prep -> gemm8(QKV) -> rope -> attn -> gemm_bt(Wo)
// ---------------------------------------------------------------------------
extern "C" void kernel_launch(void* const* d_in, const int* in_sizes, int n_in,
                              void* d_out, int out_size, void* d_ws, size_t ws_size,
                              hipStream_t stream) {
  const float* x    = (const float*)d_in[0];
  const float* Wqkv = (const float*)d_in[1];
  const float* Wo   = (const float*)d_in[2];
  float* out = (float*)d_out;
  char* ws = (char*)d_ws;

  constexpr size_t TAB_OFF  = 0;                       // 512KB
  constexpr size_t XB_OFF   = TAB_OFF + 524288;        // 8MB
  constexpr size_t WQB_OFF  = XB_OFF + 8388608;        // 6MB
  constexpr size_t WOB_OFF  = WQB_OFF + 6291456;       // 2MB
  constexpr size_t QKV_OFF  = WOB_OFF + 2097152;       // 24MB
  constexpr size_t QR_OFF   = QKV_OFF + 25165824;      // 8MB
  constexpr size_t KR_OFF   = QR_OFF + 8388608;        // 8MB
  constexpr size_t VT_OFF   = KR_OFF + 8388608;        // 8MB
  constexpr size_t AO_OFF   = VT_OFF + 8388608;        // 8MB

  float2* tab = (float2*)(ws + TAB_OFF);
  u16* xb     = (u16*)(ws + XB_OFF);
  u16* wqkvb  = (u16*)(ws + WQB_OFF);
  u16* wob    = (u16*)(ws + WOB_OFF);
  u16* qkv    = (u16*)(ws + QKV_OFF);
  u16* q_r    = (u16*)(ws + QR_OFF);
  u16* k_r    = (u16*)(ws + KR_OFF);
  u16* vt     = (u16*)(ws + VT_OFF);
  u16* ao     = (u16*)(ws + AO_OFF);

  prep_kernel<<<2048, 256, 0, stream>>>(x, Wqkv, Wo, xb, wqkvb, wob, tab);

  // allow 128KB dynamic LDS for gemm8 (idempotent; rc ignored)
  (void)hipFuncSetAttribute((const void*)gemm8_kernel,
                            hipFuncAttributeMaxDynamicSharedMemorySize, 131072);

  // qkv = x @ Wqkv^T, 8-phase 256^2 kernel (grid 12x16 = 192, %8 == 0)
  gemm8_kernel<<<dim3(3 * Dd / 256, Mm / 256), 512, 131072, stream>>>(
      xb, wqkvb, qkv, Mm, 3 * Dd, Dd);

  rope_kernel<<<dim3(Ss / 64, Bb * Hh), 256, 0, stream>>>(qkv, tab, q_r, k_r, vt);

  attn_kernel<<<dim3(NT / 2, Bb * Hh), 512, 0, stream>>>(q_r, k_r, vt, ao);

  gemm_bt_kernel<<<dim3(Dd / 128, Mm / 128), 256, 0, stream>>>(
      ao, wob, out, Mm, Dd, Dd);
}

// Round 15
// 116.863 us; speedup vs baseline: 1.1885x; 1.0045x over previous
//
#include <hip/hip_runtime.h>
#include <hip/hip_bf16.h>
#include <cstdint>
#include <cstddef>

// ---------------------------------------------------------------------------
// Fused MHA block: x@Wqkv^T -> RoPE -> causal flash attention -> @Wo^T
// B=2 S=2048 H=16 DK=64. fp32 in/out, bf16 MFMA compute (fp32 accum).
//
// R15 = R14 with compile fix: no LDS pointer arrays (addrspacecast static
// init error); regions computed inline as asmem + buf*4096 etc.
// R14 theory: attn T15 pipeline — QK(kt+1) issued BEFORE softmax+PV(kt)
// (QK MFMA overlaps prev tile's exp2/pack VALU). 3-deep KV ring keeps
// 1 barrier/iter:
//   iter kt: commit(kt+2)->buf[(kt+2)%3]  (last readers behind iter-(kt-1)
//            barrier); QK(kt+1)<-buf[(kt+1)%3] (committed iter kt-1);
//            softmax+PV(kt)<-buf[kt%3]; issue(kt+3); barrier.
// LDS 64KB dynamic (3x(K8+V8)+P16KB) -> 2 blocks/CU; saP/saN +32 VGPR.
// ---------------------------------------------------------------------------

typedef unsigned short u16;
typedef unsigned int   u32;

typedef float f32x4 __attribute__((ext_vector_type(4)));
typedef short frag_t __attribute__((ext_vector_type(8)));

__device__ __forceinline__ f32x4 mfma16(frag_t a, frag_t b, f32x4 c) {
  return __builtin_amdgcn_mfma_f32_16x16x32_bf16(a, b, c, 0, 0, 0);
}

typedef __attribute__((address_space(1))) void as1_void;
typedef __attribute__((address_space(3))) void as3_void;
__device__ __forceinline__ void gload_lds16(const void* g, void* l) {
  __builtin_amdgcn_global_load_lds((as1_void*)g, (as3_void*)l, 16, 0, 0);
}

__device__ __forceinline__ u16 f2bf(float f) {  // RNE fp32 -> bf16
  u32 u = __builtin_bit_cast(u32, f);
  u += 0x7fffu + ((u >> 16) & 1u);
  return (u16)(u >> 16);
}
__device__ __forceinline__ float bf2f(u16 h) {
  u32 u = ((u32)h) << 16;
  return __builtin_bit_cast(float, u);
}
__device__ __forceinline__ u16 bf16u(float f) {  // via compiler cvt path
  __hip_bfloat16 h = __float2bfloat16(f);
  u16 u;
  __builtin_memcpy(&u, &h, 2);
  return u;
}
__device__ __forceinline__ float exp2_hw(float x) {  // raw v_exp_f32
  float r;
  asm("v_exp_f32 %0, %1" : "=v"(r) : "v"(x));
  return r;
}
__device__ __forceinline__ void schedb() { __builtin_amdgcn_sched_barrier(0); }

static constexpr int Bb = 2, Ss = 2048, Hh = 16, Dd = 1024;
static constexpr int Mm = Bb * Ss;  // 4096
static constexpr int NT = Ss / 64;  // 32 k/q tiles

// ---------------------------------------------------------------------------
// 0) prep: rope cos/sin table + all three fp32->bf16 converts, one launch.
// ---------------------------------------------------------------------------
__global__ __launch_bounds__(256) void prep_kernel(const float* __restrict__ x,
                                                   const float* __restrict__ wqkv,
                                                   const float* __restrict__ wo,
                                                   u16* __restrict__ xb,
                                                   u16* __restrict__ wqkvb,
                                                   u16* __restrict__ wob,
                                                   float2* __restrict__ tab) {
  const int bid = blockIdx.x, tid = threadIdx.x;

  if (bid < 256) {  // rope table: 2048*32 entries, one per thread
    const int i = bid * 256 + tid;
    const int s = i >> 5, j = i & 31;
    const float log2_theta_over_32 = 0.41524101186091903f;  // log2(10000)/32
    float inv = exp2f(-(float)j * log2_theta_over_32);
    float fr = (float)s * inv;
    float sn, cs;
    sincosf(fr, &sn, &cs);
    tab[i] = make_float2(cs, sn);
  }

  const int N1 = Mm * Dd / 4;
  const int N2 = N1 + 3 * Dd * Dd / 4;
  const int N3 = N2 + Dd * Dd / 4;
  for (int idx = bid * 256 + tid; idx < N3; idx += gridDim.x * 256) {
    const float4* src;
    u16* dst;
    int off;
    if (idx < N1)      { src = (const float4*)x;    dst = xb;    off = idx; }
    else if (idx < N2) { src = (const float4*)wqkv; dst = wqkvb; off = idx - N1; }
    else               { src = (const float4*)wo;   dst = wob;   off = idx - N2; }
    float4 v = src[off];
    ushort4 o;
    o.x = f2bf(v.x); o.y = f2bf(v.y); o.z = f2bf(v.z); o.w = f2bf(v.w);
    ((ushort4*)dst)[off] = o;
  }
}

// ---------------------------------------------------------------------------
// 1a) QKV GEMM: 8-phase 256x256 schedule (R13 verbatim). bf16 out.
// ---------------------------------------------------------------------------
__global__ __launch_bounds__(512, 2) void gemm8_kernel(const u16* __restrict__ A,
                                                       const u16* __restrict__ Bm,
                                                       u16* __restrict__ C,
                                                       int Mdim, int Ndim, int Kdim) {
  extern __shared__ __align__(16) u16 smem[];
  u16* As0 = smem;              // [256][64]
  u16* As1 = smem + 16384;
  u16* Bs0 = smem + 32768;
  u16* Bs1 = smem + 49152;

  const int tid = threadIdx.x;
  const int lane = tid & 63, wid = tid >> 6;  // 8 waves
  const int wr = wid >> 2, wc = wid & 3;      // 2 x 4
  const int lr = lane & 15, lg = lane >> 4;
  const int swk = lr & 7;                     // read-side XOR key

  // T1 XCD swizzle (nwg = 192, %8 == 0)
  const int nwg = gridDim.x * gridDim.y;
  const int orig = blockIdx.y * gridDim.x + blockIdx.x;
  const int cpx = nwg >> 3;
  const int swz = (orig & 7) * cpx + (orig >> 3);
  const int bx = swz % gridDim.x, by = swz / gridDim.x;
  const int m0 = by * 256, n0 = bx * 256;

  f32x4 acc[8][4] = {};

  const int strow = tid >> 3;  // 0..63
  const int sgr = tid & 7;

  auto stage_half = [&](u16* region, const u16* src, int grow0, int kt) {
#pragma unroll
    for (int rnd = 0; rnd < 2; rnd++) {
      const int lrow = rnd * 64 + strow;
      const u16* g = src + (size_t)(grow0 + lrow) * Kdim + kt * 64 +
                     ((sgr ^ (lrow & 7)) * 8);
      gload_lds16(g, region + (rnd * 64 + wid * 8) * 64);
    }
  };

  const int NK = Kdim >> 6;  // 16

  stage_half(As0, A, m0, 0);         stage_half(As0 + 8192, A, m0 + 128, 0);
  stage_half(Bs0, Bm, n0, 0);        stage_half(Bs0 + 8192, Bm, n0 + 128, 0);
  stage_half(Bs1, Bm, n0, 1);        stage_half(Bs1 + 8192, Bm, n0 + 128, 1);
  stage_half(As1, A, m0, 1);         stage_half(As1 + 8192, A, m0 + 128, 1);
  asm volatile("s_waitcnt vmcnt(8)" ::: "memory");
  schedb();
  __builtin_amdgcn_s_barrier();
  schedb();

  for (int kt = 0; kt < NK; kt++) {
    u16* Acur = (kt & 1) ? As1 : As0;
    u16* Bcur = (kt & 1) ? Bs1 : Bs0;
    const bool more = (kt + 2 < NK);
    frag_t bfr[4][2];

#pragma unroll
    for (int q = 0; q < 4; q++) {
      frag_t a[2][2];
#pragma unroll
      for (int mm = 0; mm < 2; mm++)
#pragma unroll
        for (int ks = 0; ks < 2; ks++)
          a[mm][ks] = *(const frag_t*)&Acur[(wr * 128 + (q * 2 + mm) * 16 + lr) * 64 +
                                            (((ks * 4 + lg) ^ swk) * 8)];
      if (q == 0) {
#pragma unroll
        for (int nt = 0; nt < 4; nt++)
#pragma unroll
          for (int ks = 0; ks < 2; ks++)
            bfr[nt][ks] = *(const frag_t*)&Bcur[(wc * 64 + nt * 16 + lr) * 64 +
                                                (((ks * 4 + lg) ^ swk) * 8)];
      }
      if (q == 1 && more) stage_half(Bcur, Bm, n0, kt + 2);
      if (q == 2 && more) stage_half(Bcur + 8192, Bm, n0 + 128, kt + 2);

      schedb();
      __builtin_amdgcn_s_barrier();
      schedb();
      __builtin_amdgcn_s_setprio(1);
#pragma unroll
      for (int ks = 0; ks < 2; ks++)
#pragma unroll
        for (int mm = 0; mm < 2; mm++)
#pragma unroll
          for (int nt = 0; nt < 4; nt++)
            acc[q * 2 + mm][nt] = mfma16(a[mm][ks], bfr[nt][ks], acc[q * 2 + mm][nt]);
      __builtin_amdgcn_s_setprio(0);
      __builtin_amdgcn_s_barrier();
      schedb();
    }

    if (kt + 1 < NK) {
      if (more) {
        stage_half(Acur, A, m0, kt + 2);
        stage_half(Acur + 8192, A, m0 + 128, kt + 2);
        asm volatile("s_waitcnt vmcnt(8)" ::: "memory");
      } else {
        asm volatile("s_waitcnt vmcnt(0)" ::: "memory");
      }
      schedb();
      __builtin_amdgcn_s_barrier();
      schedb();
    }
  }

#pragma unroll
  for (int m = 0; m < 8; m++)
#pragma unroll
    for (int n = 0; n < 4; n++)
#pragma unroll
      for (int r = 0; r < 4; r++) {
        size_t row = (size_t)(m0 + wr * 128 + m * 16 + lg * 4 + r);
        size_t col = (size_t)(n0 + wc * 64 + n * 16 + lr);
        C[row * Ndim + col] = f2bf(acc[m][n][r]);
      }
}

// ---------------------------------------------------------------------------
// 1b) Wo GEMM: R9/R11 128x128 2-phase kernel (verified conflicts=0), fp32 out.
// ---------------------------------------------------------------------------
__global__ __launch_bounds__(256) void gemm_bt_kernel(const u16* __restrict__ A,
                                                      const u16* __restrict__ Bm,
                                                      float* __restrict__ Cv,
                                                      int Mdim, int Ndim, int Kdim) {
  __shared__ __align__(16) u16 As[2][128 * 64];
  __shared__ __align__(16) u16 Bs[2][128 * 64];
  const int tid = threadIdx.x;
  const int lane = tid & 63, wid = tid >> 6;
  const int wr = wid >> 1, wc = wid & 1;
  const int lr = lane & 15, lg = lane >> 4;

  const int nwg = gridDim.x * gridDim.y;
  const int orig = blockIdx.y * gridDim.x + blockIdx.x;
  const int cpx = nwg >> 3;
  const int swz = (orig & 7) * cpx + (orig >> 3);
  const int bx = swz % gridDim.x, by = swz / gridDim.x;
  const int m0 = by * 128, n0 = bx * 128;

  f32x4 acc[4][4] = {};

  const int rowA = lane >> 3;
  const int colu = ((lane & 7) ^ rowA) * 8;

  auto stage = [&](int buf, int kt) {
#pragma unroll
    for (int i = 0; i < 4; i++) {
      int chunk = wid * 4 + i;
      const u16* ga = A + (size_t)(m0 + chunk * 8 + rowA) * Kdim + kt + colu;
      gload_lds16(ga, &As[buf][chunk * 512]);
      const u16* gb = Bm + (size_t)(n0 + chunk * 8 + rowA) * Kdim + kt + colu;
      gload_lds16(gb, &Bs[buf][chunk * 512]);
    }
  };

  const int niter = Kdim >> 6;

  stage(0, 0);
  stage(1, 64);
  asm volatile("s_waitcnt vmcnt(8)" ::: "memory");
  schedb();
  __builtin_amdgcn_s_barrier();
  schedb();

  const int rsw = (lr & 7) * 8;
  int cur = 0;
  for (int it = 0; it < niter; ++it) {
#pragma unroll
    for (int ks = 0; ks < 2; ks++) {
      frag_t a[4], b[4];
#pragma unroll
      for (int mt = 0; mt < 4; mt++)
        a[mt] = *(const frag_t*)&As[cur][(wr * 64 + mt * 16 + lr) * 64 +
                                         ((ks * 32 + lg * 8) ^ rsw)];
#pragma unroll
      for (int nt = 0; nt < 4; nt++)
        b[nt] = *(const frag_t*)&Bs[cur][(wc * 64 + nt * 16 + lr) * 64 +
                                         ((ks * 32 + lg * 8) ^ rsw)];
#pragma unroll
      for (int mt = 0; mt < 4; mt++)
#pragma unroll
        for (int nt = 0; nt < 4; nt++)
          acc[mt][nt] = mfma16(a[mt], b[nt], acc[mt][nt]);
    }

    if (it + 1 < niter) {
      __builtin_amdgcn_s_barrier();
      schedb();
      if (it + 2 < niter) {
        stage(cur, (it + 2) << 6);
        asm volatile("s_waitcnt vmcnt(8)" ::: "memory");
      } else {
        asm volatile("s_waitcnt vmcnt(0)" ::: "memory");
      }
      schedb();
      __builtin_amdgcn_s_barrier();
      schedb();
      cur ^= 1;
    }
  }

#pragma unroll
  for (int mt = 0; mt < 4; mt++)
#pragma unroll
    for (int nt = 0; nt < 4; nt++)
#pragma unroll
      for (int r = 0; r < 4; r++) {
        size_t row = (size_t)(m0 + wr * 64 + mt * 16 + lg * 4 + r);
        size_t col = (size_t)(n0 + wc * 64 + nt * 16 + lr);
        Cv[row * Ndim + col] = acc[mt][nt][r];
      }
}

// ---------------------------------------------------------------------------
// 2) RoPE + reshape (R11 verbatim). Q pre-scaled by 0.125*log2(e).
// ---------------------------------------------------------------------------
__global__ __launch_bounds__(256) void rope_kernel(const u16* __restrict__ qkv,
                                                   const float2* __restrict__ tab,
                                                   u16* __restrict__ q_r,
                                                   u16* __restrict__ k_r,
                                                   u16* __restrict__ vt) {
  const int bh = blockIdx.y, b = bh >> 4, h = bh & 15;
  const int s0 = blockIdx.x * 64;
  const int t = threadIdx.x;
  __shared__ __align__(16) u16 Vls[64 * 72];

  const int srow = t >> 2, c4 = t & 3;
  const int s = s0 + srow;
  const size_t rowbase = (size_t)(b * Ss + s) * 3072 + h * 64 + c4 * 16;

  u16 xq[16] __attribute__((aligned(16)));
  u16 xk[16] __attribute__((aligned(16)));
  u16 xv[16] __attribute__((aligned(16)));
  *(uint4*)&xq[0] = *(const uint4*)(qkv + rowbase);
  *(uint4*)&xq[8] = *(const uint4*)(qkv + rowbase + 8);
  *(uint4*)&xk[0] = *(const uint4*)(qkv + rowbase + 1024);
  *(uint4*)&xk[8] = *(const uint4*)(qkv + rowbase + 1024 + 8);
  *(uint4*)&xv[0] = *(const uint4*)(qkv + rowbase + 2048);
  *(uint4*)&xv[8] = *(const uint4*)(qkv + rowbase + 2048 + 8);

  u16 oq[16] __attribute__((aligned(16)));
  u16 ok[16] __attribute__((aligned(16)));
  const int j0 = c4 * 8;
  const float qscale = 0.125f * 1.4426950408889634f;  // 1/sqrt(64) * log2(e)
#pragma unroll
  for (int p = 0; p < 8; p++) {
    float2 cs = tab[s * 32 + j0 + p];
    float q1 = bf2f(xq[2 * p]), q2 = bf2f(xq[2 * p + 1]);
    float k1 = bf2f(xk[2 * p]), k2 = bf2f(xk[2 * p + 1]);
    oq[2 * p]     = f2bf((q1 * cs.x - q2 * cs.y) * qscale);
    oq[2 * p + 1] = f2bf((q1 * cs.y + q2 * cs.x) * qscale);
    ok[2 * p]     = f2bf(k1 * cs.x - k2 * cs.y);
    ok[2 * p + 1] = f2bf(k1 * cs.y + k2 * cs.x);
  }
  const size_t obase = ((size_t)bh * Ss + s) * 64 + c4 * 16;
  *(uint4*)(q_r + obase)     = *(uint4*)&oq[0];
  *(uint4*)(q_r + obase + 8) = *(uint4*)&oq[8];
  *(uint4*)(k_r + obase)     = *(uint4*)&ok[0];
  *(uint4*)(k_r + obase + 8) = *(uint4*)&ok[8];

  *(uint4*)&Vls[srow * 72 + c4 * 16]     = *(uint4*)&xv[0];
  *(uint4*)&Vls[srow * 72 + c4 * 16 + 8] = *(uint4*)&xv[8];
  __syncthreads();
  const int d = t >> 2, cq = t & 3;
  u16 ov[16] __attribute__((aligned(16)));
#pragma unroll
  for (int i = 0; i < 16; i++) ov[i] = Vls[(cq * 16 + i) * 72 + d];
  const size_t vbase = ((size_t)bh * 64 + d) * Ss + s0 + cq * 16;
  *(uint4*)(vt + vbase)     = *(uint4*)&ov[0];
  *(uint4*)(vt + vbase + 8) = *(uint4*)&ov[8];
}

// ---------------------------------------------------------------------------
// 3) Flash attention (causal), T15-pipelined. 8 waves/block, paired q-tiles,
//    swapped QK^T, no max tracking, T2 XOR-swizzled stride-64 K/V/P LDS.
//    3-deep KV ring, 1 barrier/iter. LDS (u16 units): K[buf] @ buf*4096,
//    V[buf] @ 12288+buf*4096, P[w] @ 24576+w*1024. 64KB dynamic.
// ---------------------------------------------------------------------------
__global__ __launch_bounds__(512, 4) void attn_kernel(const u16* __restrict__ q_r,
                                                      const u16* __restrict__ k_r,
                                                      const u16* __restrict__ vt,
                                                      u16* __restrict__ o) {
  extern __shared__ __align__(16) u16 asmem[];
  const int pr = blockIdx.x;  // 0..15
  const int bh = blockIdx.y;
  const int b = bh >> 4, h = bh & 15;
  const int tid = threadIdx.x;
  const int lane = tid & 63, w = tid >> 6;
  const int ww = w & 3;
  const int lr = lane & 15, lg = lane >> 4;

  const int qt = (w < 4) ? pr : (NT - 1 - pr);  // this wave's q-tile
  const int qtB = NT - 1 - pr;                  // loop bound (>= 16)

  u16* Pw = asmem + 24576 + w * 1024;

  const size_t kvbase = (size_t)bh * Ss * 64;
  const size_t vtbase = (size_t)bh * 64 * Ss;
  const int qrow = ww * 16 + lr;
  const int sw = lr & 7;  // read-side row XOR key

  // ---- Q fragments in registers (once) ----
  frag_t q0f, q1f;
  {
    const u16* qa = q_r + kvbase + (size_t)(qt * 64 + qrow) * 64 + lg * 8;
    q0f = *(const frag_t*)qa;
    q1f = *(const frag_t*)(qa + 32);
  }

  // staging: 512 threads, one 16B chunk per tensor; LDS granule swizzled
  const int srow = tid >> 3, sgr = tid & 7;
  const int scolg = sgr * 8;
  const int scols = (sgr ^ (srow & 7)) * 8;
  uint4 kreg, vreg;
  const u16* kp = k_r + kvbase;
  const u16* vp = vt + vtbase;

  auto issue = [&](int kt) {
    kreg = *(const uint4*)(kp + (size_t)(kt * 64 + srow) * 64 + scolg);
    vreg = *(const uint4*)(vp + (size_t)srow * Ss + kt * 64 + scolg);
  };
  auto commit = [&](int buf) {
    *(uint4*)&asmem[buf * 4096 + srow * 64 + scols] = kreg;          // K
    *(uint4*)&asmem[12288 + buf * 4096 + srow * 64 + scols] = vreg;  // V
  };

  auto qk_compute = [&](int buf, f32x4* sa) {
    const u16* Kb = asmem + buf * 4096;
    __builtin_amdgcn_s_setprio(1);
#pragma unroll
    for (int kf = 0; kf < 4; kf++) {
      frag_t k0 = *(const frag_t*)&Kb[(kf * 16 + lr) * 64 + ((lg ^ sw) * 8)];
      frag_t k1 = *(const frag_t*)&Kb[(kf * 16 + lr) * 64 + (((4 + lg) ^ sw) * 8)];
      sa[kf] = mfma16(k0, q0f, f32x4{0.f, 0.f, 0.f, 0.f});
      sa[kf] = mfma16(k1, q1f, sa[kf]);
    }
    __builtin_amdgcn_s_setprio(0);
  };

  f32x4 oacc[4] = {};
  float l_run = 0.f;
  f32x4 saP[4];

  // ---- prologue: buf0, buf1 committed; saP = scores(0); regs = KV(2) ----
  issue(0);
  commit(0);
  __syncthreads();
  qk_compute(0, saP);  // kt=0 <= qt for every wave
  issue(1);
  commit(1);
  __syncthreads();
  issue(2);  // qtB >= 16 always

  for (int kt = 0; kt <= qtB; kt++) {
    const int bP = kt % 3, bN = (kt + 1) % 3, bC = (kt + 2) % 3;

    // commit KV(kt+2) -> buf[(kt+2)%3]; its last readers (QK(kt-1) at iter
    // kt-2, PV(kt-1) at iter kt-1) are behind the iter-(kt-1) barrier.
    if (kt + 2 <= qtB) commit(bC);

    // QK(kt+1) from buffer committed at iter kt-1 (visible) [MFMA pipe]
    f32x4 saN[4];
    if (kt + 1 <= qt) qk_compute(bN, saN);

    // finish tile kt: mask, exp2, pack, P->LDS, PV  [VALU + MFMA]
    if (kt <= qt) {
      if (kt == qt) {  // diagonal mask (uniform branch)
#pragma unroll
        for (int kf = 0; kf < 4; kf++)
#pragma unroll
          for (int r = 0; r < 4; r++)
            if (kf * 16 + lg * 4 + r > qrow) saP[kf][r] = -1e30f;
      }

      float ls = 0.f;
#pragma unroll
      for (int kf = 0; kf < 4; kf++) {
        float p0 = exp2_hw(saP[kf][0]), p1 = exp2_hw(saP[kf][1]);
        float p2 = exp2_hw(saP[kf][2]), p3 = exp2_hw(saP[kf][3]);
        ls += (p0 + p1) + (p2 + p3);
        ushort4 w4;
        w4.x = bf16u(p0); w4.y = bf16u(p1); w4.z = bf16u(p2); w4.w = bf16u(p3);
        const int pg = (kf * 2 + (lg >> 1)) ^ sw;
        *(ushort4*)&Pw[lr * 64 + pg * 8 + (lg & 1) * 4] = w4;
      }
      l_run += ls;

      const u16* Vb = asmem + 12288 + bP * 4096;
      __builtin_amdgcn_s_setprio(1);
#pragma unroll
      for (int ks = 0; ks < 2; ks++) {
        frag_t pa = *(const frag_t*)&Pw[lr * 64 + (((ks * 4 + lg) ^ sw) * 8)];
#pragma unroll
        for (int df = 0; df < 4; df++) {
          frag_t bv = *(const frag_t*)&Vb[(df * 16 + lr) * 64 +
                                          (((ks * 4 + lg) ^ sw) * 8)];
          oacc[df] = mfma16(pa, bv, oacc[df]);
        }
      }
      __builtin_amdgcn_s_setprio(0);
    }

    if (kt + 3 <= qtB) issue(kt + 3);

#pragma unroll
    for (int i = 0; i < 4; i++) saP[i] = saN[i];
    __syncthreads();
  }

  // ---- epilogue: reduce l across lg groups, O /= l, write bf16 ----
  l_run += __shfl_xor(l_run, 16);
  l_run += __shfl_xor(l_run, 32);
#pragma unroll
  for (int r = 0; r < 4; r++) {
    float il = 1.0f / __shfl(l_run, lg * 4 + r);
    size_t row = (size_t)b * Ss + qt * 64 + ww * 16 + lg * 4 + r;
#pragma unroll
    for (int df = 0; df < 4; df++)
      o[row * 1024 + h * 64 + df * 16 + lr] = f2bf(oacc[df][r] * il);
  }
}

// ---------------------------------------------------------------------------
// launch: prep -> gemm8(QKV) -> rope -> attn -> gemm_bt(Wo)
// ---------------------------------------------------------------------------
extern "C" void kernel_launch(void* const* d_in, const int* in_sizes, int n_in,
                              void* d_out, int out_size, void* d_ws, size_t ws_size,
                              hipStream_t stream) {
  const float* x    = (const float*)d_in[0];
  const float* Wqkv = (const float*)d_in[1];
  const float* Wo   = (const float*)d_in[2];
  float* out = (float*)d_out;
  char* ws = (char*)d_ws;

  constexpr size_t TAB_OFF  = 0;                       // 512KB
  constexpr size_t XB_OFF   = TAB_OFF + 524288;        // 8MB
  constexpr size_t WQB_OFF  = XB_OFF + 8388608;        // 6MB
  constexpr size_t WOB_OFF  = WQB_OFF + 6291456;       // 2MB
  constexpr size_t QKV_OFF  = WOB_OFF + 2097152;       // 24MB
  constexpr size_t QR_OFF   = QKV_OFF + 25165824;      // 8MB
  constexpr size_t KR_OFF   = QR_OFF + 8388608;        // 8MB
  constexpr size_t VT_OFF   = KR_OFF + 8388608;        // 8MB
  constexpr size_t AO_OFF   = VT_OFF + 8388608;        // 8MB

  float2* tab = (float2*)(ws + TAB_OFF);
  u16* xb     = (u16*)(ws + XB_OFF);
  u16* wqkvb  = (u16*)(ws + WQB_OFF);
  u16* wob    = (u16*)(ws + WOB_OFF);
  u16* qkv    = (u16*)(ws + QKV_OFF);
  u16* q_r    = (u16*)(ws + QR_OFF);
  u16* k_r    = (u16*)(ws + KR_OFF);
  u16* vt     = (u16*)(ws + VT_OFF);
  u16* ao     = (u16*)(ws + AO_OFF);

  prep_kernel<<<2048, 256, 0, stream>>>(x, Wqkv, Wo, xb, wqkvb, wob, tab);

  (void)hipFuncSetAttribute((const void*)gemm8_kernel,
                            hipFuncAttributeMaxDynamicSharedMemorySize, 131072);
  (void)hipFuncSetAttribute((const void*)attn_kernel,
                            hipFuncAttributeMaxDynamicSharedMemorySize, 65536);

  gemm8_kernel<<<dim3(3 * Dd / 256, Mm / 256), 512, 131072, stream>>>(
      xb, wqkvb, qkv, Mm, 3 * Dd, Dd);

  rope_kernel<<<dim3(Ss / 64, Bb * Hh), 256, 0, stream>>>(qkv, tab, q_r, k_r, vt);

  attn_kernel<<<dim3(NT / 2, Bb * Hh), 512, 65536, stream>>>(q_r, k_r, vt, ao);

  gemm_bt_kernel<<<dim3(Dd / 128, Mm / 128), 256, 0, stream>>>(
      ao, wob, out, Mm, Dd, Dd);
}

// Round 16
// 116.396 us; speedup vs baseline: 1.1932x; 1.0040x over previous
//
#include <hip/hip_runtime.h>
#include <hip/hip_bf16.h>
#include <cstdint>
#include <cstddef>

// ---------------------------------------------------------------------------
// Fused MHA block: x@Wqkv^T -> RoPE -> causal flash attention -> @Wo^T
// B=2 S=2048 H=16 DK=64. fp32 in/out, bf16 MFMA compute (fp32 accum).
//
// R15 = R14 with compile fix: no LDS pointer arrays (addrspacecast static
// init error); regions computed inline as asmem + buf*4096 etc.
// R14 theory: attn T15 pipeline — QK(kt+1) issued BEFORE softmax+PV(kt)
// (QK MFMA overlaps prev tile's exp2/pack VALU). 3-deep KV ring keeps
// 1 barrier/iter:
//   iter kt: commit(kt+2)->buf[(kt+2)%3]  (last readers behind iter-(kt-1)
//            barrier); QK(kt+1)<-buf[(kt+1)%3] (committed iter kt-1);
//            softmax+PV(kt)<-buf[kt%3]; issue(kt+3); barrier.
// LDS 64KB dynamic (3x(K8+V8)+P16KB) -> 2 blocks/CU; saP/saN +32 VGPR.
// ---------------------------------------------------------------------------

typedef unsigned short u16;
typedef unsigned int   u32;

typedef float f32x4 __attribute__((ext_vector_type(4)));
typedef short frag_t __attribute__((ext_vector_type(8)));

__device__ __forceinline__ f32x4 mfma16(frag_t a, frag_t b, f32x4 c) {
  return __builtin_amdgcn_mfma_f32_16x16x32_bf16(a, b, c, 0, 0, 0);
}

typedef __attribute__((address_space(1))) void as1_void;
typedef __attribute__((address_space(3))) void as3_void;
__device__ __forceinline__ void gload_lds16(const void* g, void* l) {
  __builtin_amdgcn_global_load_lds((as1_void*)g, (as3_void*)l, 16, 0, 0);
}

__device__ __forceinline__ u16 f2bf(float f) {  // RNE fp32 -> bf16
  u32 u = __builtin_bit_cast(u32, f);
  u += 0x7fffu + ((u >> 16) & 1u);
  return (u16)(u >> 16);
}
__device__ __forceinline__ float bf2f(u16 h) {
  u32 u = ((u32)h) << 16;
  return __builtin_bit_cast(float, u);
}
__device__ __forceinline__ u16 bf16u(float f) {  // via compiler cvt path
  __hip_bfloat16 h = __float2bfloat16(f);
  u16 u;
  __builtin_memcpy(&u, &h, 2);
  return u;
}
__device__ __forceinline__ float exp2_hw(float x) {  // raw v_exp_f32
  float r;
  asm("v_exp_f32 %0, %1" : "=v"(r) : "v"(x));
  return r;
}
__device__ __forceinline__ void schedb() { __builtin_amdgcn_sched_barrier(0); }

static constexpr int Bb = 2, Ss = 2048, Hh = 16, Dd = 1024;
static constexpr int Mm = Bb * Ss;  // 4096
static constexpr int NT = Ss / 64;  // 32 k/q tiles

// ---------------------------------------------------------------------------
// 0) prep: rope cos/sin table + all three fp32->bf16 converts, one launch.
// ---------------------------------------------------------------------------
__global__ __launch_bounds__(256) void prep_kernel(const float* __restrict__ x,
                                                   const float* __restrict__ wqkv,
                                                   const float* __restrict__ wo,
                                                   u16* __restrict__ xb,
                                                   u16* __restrict__ wqkvb,
                                                   u16* __restrict__ wob,
                                                   float2* __restrict__ tab) {
  const int bid = blockIdx.x, tid = threadIdx.x;

  if (bid < 256) {  // rope table: 2048*32 entries, one per thread
    const int i = bid * 256 + tid;
    const int s = i >> 5, j = i & 31;
    const float log2_theta_over_32 = 0.41524101186091903f;  // log2(10000)/32
    float inv = exp2f(-(float)j * log2_theta_over_32);
    float fr = (float)s * inv;
    float sn, cs;
    sincosf(fr, &sn, &cs);
    tab[i] = make_float2(cs, sn);
  }

  const int N1 = Mm * Dd / 4;
  const int N2 = N1 + 3 * Dd * Dd / 4;
  const int N3 = N2 + Dd * Dd / 4;
  for (int idx = bid * 256 + tid; idx < N3; idx += gridDim.x * 256) {
    const float4* src;
    u16* dst;
    int off;
    if (idx < N1)      { src = (const float4*)x;    dst = xb;    off = idx; }
    else if (idx < N2) { src = (const float4*)wqkv; dst = wqkvb; off = idx - N1; }
    else               { src = (const float4*)wo;   dst = wob;   off = idx - N2; }
    float4 v = src[off];
    ushort4 o;
    o.x = f2bf(v.x); o.y = f2bf(v.y); o.z = f2bf(v.z); o.w = f2bf(v.w);
    ((ushort4*)dst)[off] = o;
  }
}

// ---------------------------------------------------------------------------
// 1a) QKV GEMM: 8-phase 256x256 schedule (R13 verbatim). bf16 out.
// ---------------------------------------------------------------------------
__global__ __launch_bounds__(512, 2) void gemm8_kernel(const u16* __restrict__ A,
                                                       const u16* __restrict__ Bm,
                                                       u16* __restrict__ C,
                                                       int Mdim, int Ndim, int Kdim) {
  extern __shared__ __align__(16) u16 smem[];
  u16* As0 = smem;              // [256][64]
  u16* As1 = smem + 16384;
  u16* Bs0 = smem + 32768;
  u16* Bs1 = smem + 49152;

  const int tid = threadIdx.x;
  const int lane = tid & 63, wid = tid >> 6;  // 8 waves
  const int wr = wid >> 2, wc = wid & 3;      // 2 x 4
  const int lr = lane & 15, lg = lane >> 4;
  const int swk = lr & 7;                     // read-side XOR key

  // T1 XCD swizzle (nwg = 192, %8 == 0)
  const int nwg = gridDim.x * gridDim.y;
  const int orig = blockIdx.y * gridDim.x + blockIdx.x;
  const int cpx = nwg >> 3;
  const int swz = (orig & 7) * cpx + (orig >> 3);
  const int bx = swz % gridDim.x, by = swz / gridDim.x;
  const int m0 = by * 256, n0 = bx * 256;

  f32x4 acc[8][4] = {};

  const int strow = tid >> 3;  // 0..63
  const int sgr = tid & 7;

  auto stage_half = [&](u16* region, const u16* src, int grow0, int kt) {
#pragma unroll
    for (int rnd = 0; rnd < 2; rnd++) {
      const int lrow = rnd * 64 + strow;
      const u16* g = src + (size_t)(grow0 + lrow) * Kdim + kt * 64 +
                     ((sgr ^ (lrow & 7)) * 8);
      gload_lds16(g, region + (rnd * 64 + wid * 8) * 64);
    }
  };

  const int NK = Kdim >> 6;  // 16

  stage_half(As0, A, m0, 0);         stage_half(As0 + 8192, A, m0 + 128, 0);
  stage_half(Bs0, Bm, n0, 0);        stage_half(Bs0 + 8192, Bm, n0 + 128, 0);
  stage_half(Bs1, Bm, n0, 1);        stage_half(Bs1 + 8192, Bm, n0 + 128, 1);
  stage_half(As1, A, m0, 1);         stage_half(As1 + 8192, A, m0 + 128, 1);
  asm volatile("s_waitcnt vmcnt(8)" ::: "memory");
  schedb();
  __builtin_amdgcn_s_barrier();
  schedb();

  for (int kt = 0; kt < NK; kt++) {
    u16* Acur = (kt & 1) ? As1 : As0;
    u16* Bcur = (kt & 1) ? Bs1 : Bs0;
    const bool more = (kt + 2 < NK);
    frag_t bfr[4][2];

#pragma unroll
    for (int q = 0; q < 4; q++) {
      frag_t a[2][2];
#pragma unroll
      for (int mm = 0; mm < 2; mm++)
#pragma unroll
        for (int ks = 0; ks < 2; ks++)
          a[mm][ks] = *(const frag_t*)&Acur[(wr * 128 + (q * 2 + mm) * 16 + lr) * 64 +
                                            (((ks * 4 + lg) ^ swk) * 8)];
      if (q == 0) {
#pragma unroll
        for (int nt = 0; nt < 4; nt++)
#pragma unroll
          for (int ks = 0; ks < 2; ks++)
            bfr[nt][ks] = *(const frag_t*)&Bcur[(wc * 64 + nt * 16 + lr) * 64 +
                                                (((ks * 4 + lg) ^ swk) * 8)];
      }
      if (q == 1 && more) stage_half(Bcur, Bm, n0, kt + 2);
      if (q == 2 && more) stage_half(Bcur + 8192, Bm, n0 + 128, kt + 2);

      schedb();
      __builtin_amdgcn_s_barrier();
      schedb();
      __builtin_amdgcn_s_setprio(1);
#pragma unroll
      for (int ks = 0; ks < 2; ks++)
#pragma unroll
        for (int mm = 0; mm < 2; mm++)
#pragma unroll
          for (int nt = 0; nt < 4; nt++)
            acc[q * 2 + mm][nt] = mfma16(a[mm][ks], bfr[nt][ks], acc[q * 2 + mm][nt]);
      __builtin_amdgcn_s_setprio(0);
      __builtin_amdgcn_s_barrier();
      schedb();
    }

    if (kt + 1 < NK) {
      if (more) {
        stage_half(Acur, A, m0, kt + 2);
        stage_half(Acur + 8192, A, m0 + 128, kt + 2);
        asm volatile("s_waitcnt vmcnt(8)" ::: "memory");
      } else {
        asm volatile("s_waitcnt vmcnt(0)" ::: "memory");
      }
      schedb();
      __builtin_amdgcn_s_barrier();
      schedb();
    }
  }

#pragma unroll
  for (int m = 0; m < 8; m++)
#pragma unroll
    for (int n = 0; n < 4; n++)
#pragma unroll
      for (int r = 0; r < 4; r++) {
        size_t row = (size_t)(m0 + wr * 128 + m * 16 + lg * 4 + r);
        size_t col = (size_t)(n0 + wc * 64 + n * 16 + lr);
        C[row * Ndim + col] = f2bf(acc[m][n][r]);
      }
}

// ---------------------------------------------------------------------------
// 1b) Wo GEMM: R9/R11 128x128 2-phase kernel (verified conflicts=0), fp32 out.
// ---------------------------------------------------------------------------
__global__ __launch_bounds__(256) void gemm_bt_kernel(const u16* __restrict__ A,
                                                      const u16* __restrict__ Bm,
                                                      float* __restrict__ Cv,
                                                      int Mdim, int Ndim, int Kdim) {
  __shared__ __align__(16) u16 As[2][128 * 64];
  __shared__ __align__(16) u16 Bs[2][128 * 64];
  const int tid = threadIdx.x;
  const int lane = tid & 63, wid = tid >> 6;
  const int wr = wid >> 1, wc = wid & 1;
  const int lr = lane & 15, lg = lane >> 4;

  const int nwg = gridDim.x * gridDim.y;
  const int orig = blockIdx.y * gridDim.x + blockIdx.x;
  const int cpx = nwg >> 3;
  const int swz = (orig & 7) * cpx + (orig >> 3);
  const int bx = swz % gridDim.x, by = swz / gridDim.x;
  const int m0 = by * 128, n0 = bx * 128;

  f32x4 acc[4][4] = {};

  const int rowA = lane >> 3;
  const int colu = ((lane & 7) ^ rowA) * 8;

  auto stage = [&](int buf, int kt) {
#pragma unroll
    for (int i = 0; i < 4; i++) {
      int chunk = wid * 4 + i;
      const u16* ga = A + (size_t)(m0 + chunk * 8 + rowA) * Kdim + kt + colu;
      gload_lds16(ga, &As[buf][chunk * 512]);
      const u16* gb = Bm + (size_t)(n0 + chunk * 8 + rowA) * Kdim + kt + colu;
      gload_lds16(gb, &Bs[buf][chunk * 512]);
    }
  };

  const int niter = Kdim >> 6;

  stage(0, 0);
  stage(1, 64);
  asm volatile("s_waitcnt vmcnt(8)" ::: "memory");
  schedb();
  __builtin_amdgcn_s_barrier();
  schedb();

  const int rsw = (lr & 7) * 8;
  int cur = 0;
  for (int it = 0; it < niter; ++it) {
#pragma unroll
    for (int ks = 0; ks < 2; ks++) {
      frag_t a[4], b[4];
#pragma unroll
      for (int mt = 0; mt < 4; mt++)
        a[mt] = *(const frag_t*)&As[cur][(wr * 64 + mt * 16 + lr) * 64 +
                                         ((ks * 32 + lg * 8) ^ rsw)];
#pragma unroll
      for (int nt = 0; nt < 4; nt++)
        b[nt] = *(const frag_t*)&Bs[cur][(wc * 64 + nt * 16 + lr) * 64 +
                                         ((ks * 32 + lg * 8) ^ rsw)];
#pragma unroll
      for (int mt = 0; mt < 4; mt++)
#pragma unroll
        for (int nt = 0; nt < 4; nt++)
          acc[mt][nt] = mfma16(a[mt], b[nt], acc[mt][nt]);
    }

    if (it + 1 < niter) {
      __builtin_amdgcn_s_barrier();
      schedb();
      if (it + 2 < niter) {
        stage(cur, (it + 2) << 6);
        asm volatile("s_waitcnt vmcnt(8)" ::: "memory");
      } else {
        asm volatile("s_waitcnt vmcnt(0)" ::: "memory");
      }
      schedb();
      __builtin_amdgcn_s_barrier();
      schedb();
      cur ^= 1;
    }
  }

#pragma unroll
  for (int mt = 0; mt < 4; mt++)
#pragma unroll
    for (int nt = 0; nt < 4; nt++)
#pragma unroll
      for (int r = 0; r < 4; r++) {
        size_t row = (size_t)(m0 + wr * 64 + mt * 16 + lg * 4 + r);
        size_t col = (size_t)(n0 + wc * 64 + nt * 16 + lr);
        Cv[row * Ndim + col] = acc[mt][nt][r];
      }
}

// ---------------------------------------------------------------------------
// 2) RoPE + reshape (R11 verbatim). Q pre-scaled by 0.125*log2(e).
// ---------------------------------------------------------------------------
__global__ __launch_bounds__(256) void rope_kernel(const u16* __restrict__ qkv,
                                                   const float2* __restrict__ tab,
                                                   u16* __restrict__ q_r,
                                                   u16* __restrict__ k_r,
                                                   u16* __restrict__ vt) {
  const int bh = blockIdx.y, b = bh >> 4, h = bh & 15;
  const int s0 = blockIdx.x * 64;
  const int t = threadIdx.x;
  __shared__ __align__(16) u16 Vls[64 * 72];

  const int srow = t >> 2, c4 = t & 3;
  const int s = s0 + srow;
  const size_t rowbase = (size_t)(b * Ss + s) * 3072 + h * 64 + c4 * 16;

  u16 xq[16] __attribute__((aligned(16)));
  u16 xk[16] __attribute__((aligned(16)));
  u16 xv[16] __attribute__((aligned(16)));
  *(uint4*)&xq[0] = *(const uint4*)(qkv + rowbase);
  *(uint4*)&xq[8] = *(const uint4*)(qkv + rowbase + 8);
  *(uint4*)&xk[0] = *(const uint4*)(qkv + rowbase + 1024);
  *(uint4*)&xk[8] = *(const uint4*)(qkv + rowbase + 1024 + 8);
  *(uint4*)&xv[0] = *(const uint4*)(qkv + rowbase + 2048);
  *(uint4*)&xv[8] = *(const uint4*)(qkv + rowbase + 2048 + 8);

  u16 oq[16] __attribute__((aligned(16)));
  u16 ok[16] __attribute__((aligned(16)));
  const int j0 = c4 * 8;
  const float qscale = 0.125f * 1.4426950408889634f;  // 1/sqrt(64) * log2(e)
#pragma unroll
  for (int p = 0; p < 8; p++) {
    float2 cs = tab[s * 32 + j0 + p];
    float q1 = bf2f(xq[2 * p]), q2 = bf2f(xq[2 * p + 1]);
    float k1 = bf2f(xk[2 * p]), k2 = bf2f(xk[2 * p + 1]);
    oq[2 * p]     = f2bf((q1 * cs.x - q2 * cs.y) * qscale);
    oq[2 * p + 1] = f2bf((q1 * cs.y + q2 * cs.x) * qscale);
    ok[2 * p]     = f2bf(k1 * cs.x - k2 * cs.y);
    ok[2 * p + 1] = f2bf(k1 * cs.y + k2 * cs.x);
  }
  const size_t obase = ((size_t)bh * Ss + s) * 64 + c4 * 16;
  *(uint4*)(q_r + obase)     = *(uint4*)&oq[0];
  *(uint4*)(q_r + obase + 8) = *(uint4*)&oq[8];
  *(uint4*)(k_r + obase)     = *(uint4*)&ok[0];
  *(uint4*)(k_r + obase + 8) = *(uint4*)&ok[8];

  *(uint4*)&Vls[srow * 72 + c4 * 16]     = *(uint4*)&xv[0];
  *(uint4*)&Vls[srow * 72 + c4 * 16 + 8] = *(uint4*)&xv[8];
  __syncthreads();
  const int d = t >> 2, cq = t & 3;
  u16 ov[16] __attribute__((aligned(16)));
#pragma unroll
  for (int i = 0; i < 16; i++) ov[i] = Vls[(cq * 16 + i) * 72 + d];
  const size_t vbase = ((size_t)bh * 64 + d) * Ss + s0 + cq * 16;
  *(uint4*)(vt + vbase)     = *(uint4*)&ov[0];
  *(uint4*)(vt + vbase + 8) = *(uint4*)&ov[8];
}

// ---------------------------------------------------------------------------
// 3) Flash attention (causal), T15-pipelined. 8 waves/block, paired q-tiles,
//    swapped QK^T, no max tracking, T2 XOR-swizzled stride-64 K/V/P LDS.
//    3-deep KV ring, 1 barrier/iter. LDS (u16 units): K[buf] @ buf*4096,
//    V[buf] @ 12288+buf*4096, P[w] @ 24576+w*1024. 64KB dynamic.
// ---------------------------------------------------------------------------
__global__ __launch_bounds__(512, 4) void attn_kernel(const u16* __restrict__ q_r,
                                                      const u16* __restrict__ k_r,
                                                      const u16* __restrict__ vt,
                                                      u16* __restrict__ o) {
  extern __shared__ __align__(16) u16 asmem[];
  const int pr = blockIdx.x;  // 0..15
  const int bh = blockIdx.y;
  const int b = bh >> 4, h = bh & 15;
  const int tid = threadIdx.x;
  const int lane = tid & 63, w = tid >> 6;
  const int ww = w & 3;
  const int lr = lane & 15, lg = lane >> 4;

  const int qt = (w < 4) ? pr : (NT - 1 - pr);  // this wave's q-tile
  const int qtB = NT - 1 - pr;                  // loop bound (>= 16)

  u16* Pw = asmem + 24576 + w * 1024;

  const size_t kvbase = (size_t)bh * Ss * 64;
  const size_t vtbase = (size_t)bh * 64 * Ss;
  const int qrow = ww * 16 + lr;
  const int sw = lr & 7;  // read-side row XOR key

  // ---- Q fragments in registers (once) ----
  frag_t q0f, q1f;
  {
    const u16* qa = q_r + kvbase + (size_t)(qt * 64 + qrow) * 64 + lg * 8;
    q0f = *(const frag_t*)qa;
    q1f = *(const frag_t*)(qa + 32);
  }

  // staging: 512 threads, one 16B chunk per tensor; LDS granule swizzled
  const int srow = tid >> 3, sgr = tid & 7;
  const int scolg = sgr * 8;
  const int scols = (sgr ^ (srow & 7)) * 8;
  uint4 kreg, vreg;
  const u16* kp = k_r + kvbase;
  const u16* vp = vt + vtbase;

  auto issue = [&](int kt) {
    kreg = *(const uint4*)(kp + (size_t)(kt * 64 + srow) * 64 + scolg);
    vreg = *(const uint4*)(vp + (size_t)srow * Ss + kt * 64 + scolg);
  };
  auto commit = [&](int buf) {
    *(uint4*)&asmem[buf * 4096 + srow * 64 + scols] = kreg;          // K
    *(uint4*)&asmem[12288 + buf * 4096 + srow * 64 + scols] = vreg;  // V
  };

  auto qk_compute = [&](int buf, f32x4* sa) {
    const u16* Kb = asmem + buf * 4096;
    __builtin_amdgcn_s_setprio(1);
#pragma unroll
    for (int kf = 0; kf < 4; kf++) {
      frag_t k0 = *(const frag_t*)&Kb[(kf * 16 + lr) * 64 + ((lg ^ sw) * 8)];
      frag_t k1 = *(const frag_t*)&Kb[(kf * 16 + lr) * 64 + (((4 + lg) ^ sw) * 8)];
      sa[kf] = mfma16(k0, q0f, f32x4{0.f, 0.f, 0.f, 0.f});
      sa[kf] = mfma16(k1, q1f, sa[kf]);
    }
    __builtin_amdgcn_s_setprio(0);
  };

  f32x4 oacc[4] = {};
  float l_run = 0.f;
  f32x4 saP[4];

  // ---- prologue: buf0, buf1 committed; saP = scores(0); regs = KV(2) ----
  issue(0);
  commit(0);
  __syncthreads();
  qk_compute(0, saP);  // kt=0 <= qt for every wave
  issue(1);
  commit(1);
  __syncthreads();
  issue(2);  // qtB >= 16 always

  for (int kt = 0; kt <= qtB; kt++) {
    const int bP = kt % 3, bN = (kt + 1) % 3, bC = (kt + 2) % 3;

    // commit KV(kt+2) -> buf[(kt+2)%3]; its last readers (QK(kt-1) at iter
    // kt-2, PV(kt-1) at iter kt-1) are behind the iter-(kt-1) barrier.
    if (kt + 2 <= qtB) commit(bC);

    // QK(kt+1) from buffer committed at iter kt-1 (visible) [MFMA pipe]
    f32x4 saN[4];
    if (kt + 1 <= qt) qk_compute(bN, saN);

    // finish tile kt: mask, exp2, pack, P->LDS, PV  [VALU + MFMA]
    if (kt <= qt) {
      if (kt == qt) {  // diagonal mask (uniform branch)
#pragma unroll
        for (int kf = 0; kf < 4; kf++)
#pragma unroll
          for (int r = 0; r < 4; r++)
            if (kf * 16 + lg * 4 + r > qrow) saP[kf][r] = -1e30f;
      }

      float ls = 0.f;
#pragma unroll
      for (int kf = 0; kf < 4; kf++) {
        float p0 = exp2_hw(saP[kf][0]), p1 = exp2_hw(saP[kf][1]);
        float p2 = exp2_hw(saP[kf][2]), p3 = exp2_hw(saP[kf][3]);
        ls += (p0 + p1) + (p2 + p3);
        ushort4 w4;
        w4.x = bf16u(p0); w4.y = bf16u(p1); w4.z = bf16u(p2); w4.w = bf16u(p3);
        const int pg = (kf * 2 + (lg >> 1)) ^ sw;
        *(ushort4*)&Pw[lr * 64 + pg * 8 + (lg & 1) * 4] = w4;
      }
      l_run += ls;

      const u16* Vb = asmem + 12288 + bP * 4096;
      __builtin_amdgcn_s_setprio(1);
#pragma unroll
      for (int ks = 0; ks < 2; ks++) {
        frag_t pa = *(const frag_t*)&Pw[lr * 64 + (((ks * 4 + lg) ^ sw) * 8)];
#pragma unroll
        for (int df = 0; df < 4; df++) {
          frag_t bv = *(const frag_t*)&Vb[(df * 16 + lr) * 64 +
                                          (((ks * 4 + lg) ^ sw) * 8)];
          oacc[df] = mfma16(pa, bv, oacc[df]);
        }
      }
      __builtin_amdgcn_s_setprio(0);
    }

    if (kt + 3 <= qtB) issue(kt + 3);

#pragma unroll
    for (int i = 0; i < 4; i++) saP[i] = saN[i];
    __syncthreads();
  }

  // ---- epilogue: reduce l across lg groups, O /= l, write bf16 ----
  l_run += __shfl_xor(l_run, 16);
  l_run += __shfl_xor(l_run, 32);
#pragma unroll
  for (int r = 0; r < 4; r++) {
    float il = 1.0f / __shfl(l_run, lg * 4 + r);
    size_t row = (size_t)b * Ss + qt * 64 + ww * 16 + lg * 4 + r;
#pragma unroll
    for (int df = 0; df < 4; df++)
      o[row * 1024 + h * 64 + df * 16 + lr] = f2bf(oacc[df][r] * il);
  }
}

// ---------------------------------------------------------------------------
// launch: prep -> gemm8(QKV) -> rope -> attn -> gemm_bt(Wo)
// ---------------------------------------------------------------------------
extern "C" void kernel_launch(void* const* d_in, const int* in_sizes, int n_in,
                              void* d_out, int out_size, void* d_ws, size_t ws_size,
                              hipStream_t stream) {
  const float* x    = (const float*)d_in[0];
  const float* Wqkv = (const float*)d_in[1];
  const float* Wo   = (const float*)d_in[2];
  float* out = (float*)d_out;
  char* ws = (char*)d_ws;

  constexpr size_t TAB_OFF  = 0;                       // 512KB
  constexpr size_t XB_OFF   = TAB_OFF + 524288;        // 8MB
  constexpr size_t WQB_OFF  = XB_OFF + 8388608;        // 6MB
  constexpr size_t WOB_OFF  = WQB_OFF + 6291456;       // 2MB
  constexpr size_t QKV_OFF  = WOB_OFF + 2097152;       // 24MB
  constexpr size_t QR_OFF   = QKV_OFF + 25165824;      // 8MB
  constexpr size_t KR_OFF   = QR_OFF + 8388608;        // 8MB
  constexpr size_t VT_OFF   = KR_OFF + 8388608;        // 8MB
  constexpr size_t AO_OFF   = VT_OFF + 8388608;        // 8MB

  float2* tab = (float2*)(ws + TAB_OFF);
  u16* xb     = (u16*)(ws + XB_OFF);
  u16* wqkvb  = (u16*)(ws + WQB_OFF);
  u16* wob    = (u16*)(ws + WOB_OFF);
  u16* qkv    = (u16*)(ws + QKV_OFF);
  u16* q_r    = (u16*)(ws + QR_OFF);
  u16* k_r    = (u16*)(ws + KR_OFF);
  u16* vt     = (u16*)(ws + VT_OFF);
  u16* ao     = (u16*)(ws + AO_OFF);

  prep_kernel<<<2048, 256, 0, stream>>>(x, Wqkv, Wo, xb, wqkvb, wob, tab);

  (void)hipFuncSetAttribute((const void*)gemm8_kernel,
                            hipFuncAttributeMaxDynamicSharedMemorySize, 131072);
  (void)hipFuncSetAttribute((const void*)attn_kernel,
                            hipFuncAttributeMaxDynamicSharedMemorySize, 65536);

  gemm8_kernel<<<dim3(3 * Dd / 256, Mm / 256), 512, 131072, stream>>>(
      xb, wqkvb, qkv, Mm, 3 * Dd, Dd);

  rope_kernel<<<dim3(Ss / 64, Bb * Hh), 256, 0, stream>>>(qkv, tab, q_r, k_r, vt);

  attn_kernel<<<dim3(NT / 2, Bb * Hh), 512, 65536, stream>>>(q_r, k_r, vt, ao);

  gemm_bt_kernel<<<dim3(Dd / 128, Mm / 128), 256, 0, stream>>>(
      ao, wob, out, Mm, Dd, Dd);
}